// Round 2
// baseline (1084.959 us; speedup 1.0000x reference)
//
#include <hip/hip_runtime.h>
#include <hip/hip_bf16.h>

// RelationAttn: out = softmax_causal((enc @ R) @ enc^T) @ enc
// enc: [8,2048,1024] f32, R: [1024,1024] f32, out: [8,2048,1024] f32
//
// Kernel 1: Q = enc @ R (bf16 MFMA, f32 acc) -> d_out (f32).
// Kernel 2: causal flash attention, QB=32 rows/block, KVB=64, 8 symmetric waves.
//   - balanced heavy-first q-tile mapping (each CU ~33 tile-units)
//   - S-phase K-fragments direct from global (no row-major LDS staging)
//   - V^T staged bf16 in LDS (XOR-swizzled), S partials reduced via ds_add_f32
//   - all-wave softmax (4 rows/wave), 3 barriers/tile

typedef __attribute__((ext_vector_type(4))) float f32x4;
typedef __attribute__((ext_vector_type(8))) short bf16x8;
typedef __attribute__((ext_vector_type(2))) unsigned u32x2;
typedef __attribute__((ext_vector_type(4))) short short4v;

#define MFMA16(A, B, C) __builtin_amdgcn_mfma_f32_16x16x32_bf16(A, B, C, 0, 0, 0)

// pack two f32 -> two bf16 (RTZ) in one v_perm_b32
__device__ __forceinline__ unsigned pk2(float a, float b) {
    return __builtin_amdgcn_perm(__float_as_uint(b), __float_as_uint(a), 0x07060302u);
}

__device__ __forceinline__ bf16x8 cvt8(f32x4 x0, f32x4 x1) {
    union { bf16x8 v; unsigned u[4]; } r;
    r.u[0] = pk2(x0[0], x0[1]); r.u[1] = pk2(x0[2], x0[3]);
    r.u[2] = pk2(x1[0], x1[1]); r.u[3] = pk2(x1[2], x1[3]);
    return r.v;
}

__device__ __forceinline__ short f2bf(float x) {
    union { float f; unsigned u; } v; v.f = x;
    unsigned r = v.u + 0x7fffu + ((v.u >> 16) & 1u);
    return (short)(r >> 16);
}

__device__ __forceinline__ short4v cvt4(f32x4 a) {
    short4v r;
    r[0] = f2bf(a[0]); r[1] = f2bf(a[1]); r[2] = f2bf(a[2]); r[3] = f2bf(a[3]);
    return r;
}

// ---------------------------------------------------------------------------
// Kernel 1: Q = enc(16384x1024) @ R(1024x1024), 128x128 tile, 4 waves
// ---------------------------------------------------------------------------
__global__ __launch_bounds__(256) void qr_gemm_kernel(
    const float* __restrict__ A, const float* __restrict__ B, float* C)
{
    __shared__ __align__(16) char sA[128 * 64];
    __shared__ __align__(16) char sB[128 * 64];
    const int t = threadIdx.x;
    const int w = t >> 6, l = t & 63;
    const int l15 = l & 15, lg = l >> 4;
    const int bm = blockIdx.x * 128;
    const int bn = blockIdx.y * 128;

    f32x4 acc[4][4];
#pragma unroll
    for (int i = 0; i < 4; ++i)
#pragma unroll
        for (int j = 0; j < 4; ++j) acc[i][j] = (f32x4){0.f, 0.f, 0.f, 0.f};

    const int kq = 4 * (t & 7);
    const int i2 = t >> 3;

    for (int kk = 0; kk < 1024; kk += 32) {
#pragma unroll
        for (int it = 0; it < 4; ++it) {
            int m = i2 + 32 * it;
            f32x4 x = *reinterpret_cast<const f32x4*>(&A[(size_t)(bm + m) * 1024 + kk + kq]);
            *reinterpret_cast<short4v*>(sA + m * 64 + ((2 * kq) ^ (((m >> 1) & 3) << 4))) = cvt4(x);
        }
        {
            int n0 = 4 * i2;
            f32x4 x[4];
#pragma unroll
            for (int r = 0; r < 4; ++r)
                x[r] = *reinterpret_cast<const f32x4*>(&B[(size_t)(kk + kq + r) * 1024 + bn + n0]);
#pragma unroll
            for (int j = 0; j < 4; ++j) {
                int n = n0 + j;
                short4v s;
                s[0] = f2bf(x[0][j]); s[1] = f2bf(x[1][j]); s[2] = f2bf(x[2][j]); s[3] = f2bf(x[3][j]);
                *reinterpret_cast<short4v*>(sB + n * 64 + ((2 * kq) ^ (((n >> 1) & 3) << 4))) = s;
            }
        }
        __syncthreads();
        const int r0 = (w >> 1) * 64, c0 = (w & 1) * 64;
        bf16x8 af[4], bfv[4];
#pragma unroll
        for (int mt = 0; mt < 4; ++mt) {
            int m = r0 + 16 * mt + l15;
            af[mt] = *reinterpret_cast<bf16x8*>(sA + m * 64 + ((16 * lg) ^ (((m >> 1) & 3) << 4)));
        }
#pragma unroll
        for (int nt = 0; nt < 4; ++nt) {
            int n = c0 + 16 * nt + l15;
            bfv[nt] = *reinterpret_cast<bf16x8*>(sB + n * 64 + ((16 * lg) ^ (((n >> 1) & 3) << 4)));
        }
#pragma unroll
        for (int mt = 0; mt < 4; ++mt)
#pragma unroll
            for (int nt = 0; nt < 4; ++nt)
                acc[mt][nt] = MFMA16(af[mt], bfv[nt], acc[mt][nt]);
        __syncthreads();
    }
#pragma unroll
    for (int mt = 0; mt < 4; ++mt)
#pragma unroll
        for (int nt = 0; nt < 4; ++nt)
#pragma unroll
            for (int rg = 0; rg < 4; ++rg) {
                int row = bm + (w >> 1) * 64 + 16 * mt + 4 * lg + rg;
                int col = bn + (w & 1) * 64 + 16 * nt + l15;
                C[(size_t)row * 1024 + col] = acc[mt][nt][rg];
            }
}

// ---------------------------------------------------------------------------
// Kernel 2: causal flash attention. QB=32/block, KVB=64, 8 symmetric waves.
// ---------------------------------------------------------------------------
__global__ __launch_bounds__(512, 2) void attn_kernel(
    const float* __restrict__ enc, float* __restrict__ out)
{
    // V^T bf16: byte(d, kv) = d*128 + ((2*kv) ^ (((d ^ (d>>5)) & 7) << 4))
    __shared__ __align__(16) char Vb[1024 * 128];
    __shared__ __align__(16) float Sp[32][68];          // S accumulator (ds_add), padded
    __shared__ __align__(16) unsigned short Pb[32][72]; // P bf16, padded
    __shared__ float Avec[32];
    __shared__ float Linv[32];

    const int t = threadIdx.x;
    const int w = t >> 6, l = t & 63;
    const int l15 = l & 15, lg = (l >> 4) & 3;

    // balanced heavy-first q-tile mapping
    int lin = blockIdx.x, qi, b;
    if (lin < 256) { qi = 63 - (lin & 31); b = lin >> 5; }
    else           { qi = (lin - 256) & 31; b = (lin - 256) >> 5; }
    const int q0 = qi * 32;
    const size_t bofs = (size_t)b * 2048;

    const int wd = w >> 1, wn = w & 1;  // S-phase: d-slice (4) x kv-slice (2)

    // ---- Q fragments: rows q0+16mt+l15, d = 256*wd + 32*ks + 8*lg ----
    bf16x8 qreg[2][8];
#pragma unroll
    for (int mt = 0; mt < 2; ++mt)
#pragma unroll
        for (int ks = 0; ks < 8; ++ks) {
            const float* p = &out[(bofs + q0 + 16 * mt + l15) * 1024 + 256 * wd + 32 * ks + 8 * lg];
            qreg[mt][ks] = cvt8(*reinterpret_cast<const f32x4*>(p),
                                *reinterpret_cast<const f32x4*>(p + 4));
        }

    // zero Sp
    for (int i = t; i < 32 * 68; i += 512) ((float*)Sp)[i] = 0.f;

    f32x4 accO[2][8];
#pragma unroll
    for (int mt = 0; mt < 2; ++mt)
#pragma unroll
        for (int nt = 0; nt < 8; ++nt) accO[mt][nt] = (f32x4){0.f, 0.f, 0.f, 0.f};

    const int srow = 4 * w + (l >> 4);  // softmax row owned by this lane
    float m_run = -INFINITY, l_run = 0.f;

    const int g  = t >> 5;          // staging: kv rows 4g..4g+3
    const int d0 = 32 * (t & 31);   // staging: d base (contiguous 128B per lane)

    const int ntile = (qi >> 1) + 1;
    for (int tt = 0; tt < ntile; ++tt) {
        const int kv0 = tt * 64;
        __syncthreads();  // B0: prev PV done (Vb reusable); Sp zeroed/ready

        // ---- S phase: K-frags direct from global, MFMA, ds_add partials ----
        f32x4 accS[2][2];
#pragma unroll
        for (int i = 0; i < 2; ++i)
#pragma unroll
            for (int j = 0; j < 2; ++j) accS[i][j] = (f32x4){0.f, 0.f, 0.f, 0.f};
#pragma unroll
        for (int ks = 0; ks < 8; ++ks) {
            const float* kp = &enc[(bofs + kv0 + 32 * wn + l15) * 1024 + 256 * wd + 32 * ks + 8 * lg];
            bf16x8 kf0 = cvt8(*reinterpret_cast<const f32x4*>(kp),
                              *reinterpret_cast<const f32x4*>(kp + 4));
            bf16x8 kf1 = cvt8(*reinterpret_cast<const f32x4*>(kp + 16 * 1024),
                              *reinterpret_cast<const f32x4*>(kp + 16 * 1024 + 4));
            accS[0][0] = MFMA16(qreg[0][ks], kf0, accS[0][0]);
            accS[1][0] = MFMA16(qreg[1][ks], kf0, accS[1][0]);
            accS[0][1] = MFMA16(qreg[0][ks], kf1, accS[0][1]);
            accS[1][1] = MFMA16(qreg[1][ks], kf1, accS[1][1]);
        }
#pragma unroll
        for (int mt = 0; mt < 2; ++mt)
#pragma unroll
            for (int nt = 0; nt < 2; ++nt)
#pragma unroll
                for (int rg = 0; rg < 4; ++rg)
                    atomicAdd(&Sp[16 * mt + 4 * lg + rg][32 * wn + 16 * nt + l15],
                              accS[mt][nt][rg]);

        // ---- stage V^T (bf16, swizzled) ----
        {
            const float* rp = &enc[(bofs + kv0 + 4 * g) * 1024 + d0];
#pragma unroll
            for (int c = 0; c < 4; ++c) {
                f32x4 x[4][2];
#pragma unroll
                for (int r = 0; r < 4; ++r) {
                    x[r][0] = *reinterpret_cast<const f32x4*>(rp + r * 1024 + 8 * c);
                    x[r][1] = *reinterpret_cast<const f32x4*>(rp + r * 1024 + 8 * c + 4);
                }
#pragma unroll
                for (int j = 0; j < 8; ++j) {
                    int d = d0 + 8 * c + j;
                    u32x2 pv;
                    pv.x = pk2(x[0][j >> 2][j & 3], x[1][j >> 2][j & 3]);
                    pv.y = pk2(x[2][j >> 2][j & 3], x[3][j >> 2][j & 3]);
                    *reinterpret_cast<u32x2*>(
                        Vb + d * 128 + ((8 * g) ^ (((d ^ (d >> 5)) & 7) << 4))) = pv;
                }
            }
        }
        __syncthreads();  // B1: Sp + Vb visible

        // ---- softmax: all waves, 4 rows each; lane cols 4*l15..+3 ----
        {
            const int c0 = 4 * l15;
            f32x4 s = *reinterpret_cast<f32x4*>(&Sp[srow][c0]);
#pragma unroll
            for (int j = 0; j < 4; ++j)
                if (kv0 + c0 + j > q0 + srow) s[j] = -1e30f;
            float mx = fmaxf(fmaxf(s[0], s[1]), fmaxf(s[2], s[3]));
#pragma unroll
            for (int off = 1; off < 16; off <<= 1) mx = fmaxf(mx, __shfl_xor(mx, off));
            float mnew = fmaxf(m_run, mx);
            float al = __expf(m_run - mnew);
            f32x4 e; float ts = 0.f;
#pragma unroll
            for (int j = 0; j < 4; ++j) { e[j] = __expf(s[j] - mnew); ts += e[j]; }
#pragma unroll
            for (int off = 1; off < 16; off <<= 1) ts += __shfl_xor(ts, off);
            l_run = l_run * al + ts;
            m_run = mnew;
            if (l15 == 0) Avec[srow] = al;
            u32x2 pw; pw.x = pk2(e[0], e[1]); pw.y = pk2(e[2], e[3]);
            *reinterpret_cast<u32x2*>(&Pb[srow][c0]) = pw;
            *reinterpret_cast<f32x4*>(&Sp[srow][c0]) = (f32x4){0.f, 0.f, 0.f, 0.f};  // re-zero
        }
        __syncthreads();  // B2: P, Avec visible; Sp re-zeroed

        // ---- PV: all waves, O d-slice [128w, 128w+128) ----
        float af_[2][4];
#pragma unroll
        for (int mt = 0; mt < 2; ++mt)
#pragma unroll
            for (int rg = 0; rg < 4; ++rg) af_[mt][rg] = Avec[16 * mt + 4 * lg + rg];
#pragma unroll
        for (int mt = 0; mt < 2; ++mt)
#pragma unroll
            for (int nt = 0; nt < 8; ++nt)
#pragma unroll
                for (int rg = 0; rg < 4; ++rg) accO[mt][nt][rg] *= af_[mt][rg];

        bf16x8 pa[2][2];
#pragma unroll
        for (int mt = 0; mt < 2; ++mt)
#pragma unroll
            for (int kk = 0; kk < 2; ++kk)
                pa[mt][kk] = *reinterpret_cast<bf16x8*>(&Pb[16 * mt + l15][32 * kk + 8 * lg]);
#pragma unroll
        for (int nt = 0; nt < 8; ++nt) {
            const int d = 128 * w + 16 * nt + l15;
            const int swz = ((d ^ (d >> 5)) & 7) << 4;
#pragma unroll
            for (int kk = 0; kk < 2; ++kk) {
                bf16x8 vf = *reinterpret_cast<bf16x8*>(
                    Vb + d * 128 + ((64 * kk + 16 * lg) ^ swz));
                accO[0][nt] = MFMA16(pa[0][kk], vf, accO[0][nt]);
                accO[1][nt] = MFMA16(pa[1][kk], vf, accO[1][nt]);
            }
        }
    }

    // ---- finalize ----
    if (l15 == 0) Linv[srow] = 1.0f / l_run;
    __syncthreads();
    float dv[2][4];
#pragma unroll
    for (int mt = 0; mt < 2; ++mt)
#pragma unroll
        for (int rg = 0; rg < 4; ++rg) dv[mt][rg] = Linv[16 * mt + 4 * lg + rg];
#pragma unroll
    for (int mt = 0; mt < 2; ++mt)
#pragma unroll
        for (int nt = 0; nt < 8; ++nt)
#pragma unroll
            for (int rg = 0; rg < 4; ++rg) {
                size_t row = bofs + q0 + 16 * mt + 4 * lg + rg;
                int col = 128 * w + 16 * nt + l15;
                out[row * 1024 + col] = accO[mt][nt][rg] * dv[mt][rg];
            }
}

// ---------------------------------------------------------------------------
extern "C" void kernel_launch(void* const* d_in, const int* in_sizes, int n_in,
                              void* d_out, int out_size, void* d_ws, size_t ws_size,
                              hipStream_t stream)
{
    const float* enc = (const float*)d_in[0];
    const float* R = (const float*)d_in[1];
    float* out = (float*)d_out;

    qr_gemm_kernel<<<dim3(128, 8), 256, 0, stream>>>(enc, R, out);
    attn_kernel<<<dim3(512), 512, 0, stream>>>(enc, out);
}

// Round 3
// 1034.918 us; speedup vs baseline: 1.0484x; 1.0484x over previous
//
#include <hip/hip_runtime.h>
#include <hip/hip_bf16.h>

// RelationAttn: out = softmax_causal((enc @ R) @ enc^T) @ enc
// enc: [8,2048,1024] f32, R: [1024,1024] f32, out: [8,2048,1024] f32
//
// Kernel 1: Q = enc @ R (bf16 MFMA) -> d_out f32.
// Kernel 2: causal flash attention. 256 blocks (1/CU), 512 thr (8 waves).
//   Block bid: batch = bid&7 (XCD-affinity via %8 round robin), pair p = bid>>3.
//   Processes q-tiles 63-p then p (QB=32 each) -> exactly 65 KVB=32 tiles/block.
//   Per tile: reg-stage K once from global -> dual LDS layout (Kb row-major bf16,
//   Vb transposed bf16); prefetch next tile's regs during compute (lgkmcnt-only
//   barriers keep the 16 loads in flight across S/softmax/PV).

typedef __attribute__((ext_vector_type(4))) float f32x4;
typedef __attribute__((ext_vector_type(2))) float f32x2;
typedef __attribute__((ext_vector_type(8))) short bf16x8;
typedef __attribute__((ext_vector_type(4))) short short4v;
typedef __attribute__((ext_vector_type(4))) unsigned u32x4;

#define MFMA16(A, B, C) __builtin_amdgcn_mfma_f32_16x16x32_bf16(A, B, C, 0, 0, 0)

// pack two f32 -> two bf16 (RTZ) in one v_perm_b32
__device__ __forceinline__ unsigned pk2(float a, float b) {
    return __builtin_amdgcn_perm(__float_as_uint(b), __float_as_uint(a), 0x07060302u);
}

__device__ __forceinline__ bf16x8 cvt8(f32x4 x0, f32x4 x1) {
    union { bf16x8 v; unsigned u[4]; } r;
    r.u[0] = pk2(x0[0], x0[1]); r.u[1] = pk2(x0[2], x0[3]);
    r.u[2] = pk2(x1[0], x1[1]); r.u[3] = pk2(x1[2], x1[3]);
    return r.v;
}

__device__ __forceinline__ short f2bf(float x) {
    union { float f; unsigned u; } v; v.f = x;
    unsigned r = v.u + 0x7fffu + ((v.u >> 16) & 1u);
    return (short)(r >> 16);
}

__device__ __forceinline__ short4v cvt4(f32x4 a) {
    short4v r;
    r[0] = f2bf(a[0]); r[1] = f2bf(a[1]); r[2] = f2bf(a[2]); r[3] = f2bf(a[3]);
    return r;
}

// barrier that drains LDS ops only -- keeps global prefetch loads in flight
__device__ __forceinline__ void bar_lds() {
    asm volatile("s_waitcnt lgkmcnt(0)" ::: "memory");
    __builtin_amdgcn_s_barrier();
    asm volatile("" ::: "memory");
}

// ---------------------------------------------------------------------------
// Kernel 1: Q = enc(16384x1024) @ R(1024x1024), 128x128 tile, 4 waves
// ---------------------------------------------------------------------------
__global__ __launch_bounds__(256) void qr_gemm_kernel(
    const float* __restrict__ A, const float* __restrict__ B, float* C)
{
    __shared__ __align__(16) char sA[128 * 64];
    __shared__ __align__(16) char sB[128 * 64];
    const int t = threadIdx.x;
    const int w = t >> 6, l = t & 63;
    const int l15 = l & 15, lg = l >> 4;
    const int bm = blockIdx.x * 128;
    const int bn = blockIdx.y * 128;

    f32x4 acc[4][4];
#pragma unroll
    for (int i = 0; i < 4; ++i)
#pragma unroll
        for (int j = 0; j < 4; ++j) acc[i][j] = (f32x4){0.f, 0.f, 0.f, 0.f};

    const int kq = 4 * (t & 7);
    const int i2 = t >> 3;

    for (int kk = 0; kk < 1024; kk += 32) {
#pragma unroll
        for (int it = 0; it < 4; ++it) {
            int m = i2 + 32 * it;
            f32x4 x = *reinterpret_cast<const f32x4*>(&A[(size_t)(bm + m) * 1024 + kk + kq]);
            *reinterpret_cast<short4v*>(sA + m * 64 + ((2 * kq) ^ (((m >> 1) & 3) << 4))) = cvt4(x);
        }
        {
            int n0 = 4 * i2;
            f32x4 x[4];
#pragma unroll
            for (int r = 0; r < 4; ++r)
                x[r] = *reinterpret_cast<const f32x4*>(&B[(size_t)(kk + kq + r) * 1024 + bn + n0]);
#pragma unroll
            for (int j = 0; j < 4; ++j) {
                int n = n0 + j;
                short4v s;
                s[0] = f2bf(x[0][j]); s[1] = f2bf(x[1][j]); s[2] = f2bf(x[2][j]); s[3] = f2bf(x[3][j]);
                *reinterpret_cast<short4v*>(sB + n * 64 + ((2 * kq) ^ (((n >> 1) & 3) << 4))) = s;
            }
        }
        __syncthreads();
        const int r0 = (w >> 1) * 64, c0 = (w & 1) * 64;
        bf16x8 af[4], bfv[4];
#pragma unroll
        for (int mt = 0; mt < 4; ++mt) {
            int m = r0 + 16 * mt + l15;
            af[mt] = *reinterpret_cast<bf16x8*>(sA + m * 64 + ((16 * lg) ^ (((m >> 1) & 3) << 4)));
        }
#pragma unroll
        for (int nt = 0; nt < 4; ++nt) {
            int n = c0 + 16 * nt + l15;
            bfv[nt] = *reinterpret_cast<bf16x8*>(sB + n * 64 + ((16 * lg) ^ (((n >> 1) & 3) << 4)));
        }
#pragma unroll
        for (int mt = 0; mt < 4; ++mt)
#pragma unroll
            for (int nt = 0; nt < 4; ++nt)
                acc[mt][nt] = MFMA16(af[mt], bfv[nt], acc[mt][nt]);
        __syncthreads();
    }
#pragma unroll
    for (int mt = 0; mt < 4; ++mt)
#pragma unroll
        for (int nt = 0; nt < 4; ++nt)
#pragma unroll
            for (int rg = 0; rg < 4; ++rg) {
                int row = bm + (w >> 1) * 64 + 16 * mt + 4 * lg + rg;
                int col = bn + (w & 1) * 64 + 16 * nt + l15;
                C[(size_t)row * 1024 + col] = acc[mt][nt][rg];
            }
}

// ---------------------------------------------------------------------------
// Kernel 2: causal flash attention. QB=32, KVB=32, pair-balanced, XCD-affine.
// ---------------------------------------------------------------------------
__global__ __launch_bounds__(512, 2) void attn_kernel(
    const float* __restrict__ enc, float* __restrict__ out)
{
    // Kb[kv][d] bf16, row stride 2064 B (odd granule count -> bank spread)
    __shared__ __align__(16) char Kb[32 * 2064];
    // Vb[d][kv] bf16, row stride 80 B
    __shared__ __align__(16) char Vb[1024 * 80];
    __shared__ float Sp[32][34];                 // S accumulator (ds_add)
    __shared__ unsigned short Pb[32][40];        // P bf16
    __shared__ float Avec[32];
    __shared__ float Linv[32];

    const int t = threadIdx.x;
    const int w = t >> 6, l = t & 63;
    const int l15 = l & 15, lg = (l >> 4) & 3;
    const int srow = 4 * w + lg;       // softmax row owned by this lane group

    const int b = blockIdx.x & 7;      // batch -> XCD (round-robin %8)
    const int p = blockIdx.x >> 3;     // pair index 0..31
    const size_t bofs = (size_t)b * 2048;

    const int a = t & 3;               // staging: kv rows 8a..8a+7
    const int e = t >> 2;              // staging: d octet 8e..8e+7 (0..127)

    for (int i = t; i < 32 * 34; i += 512) ((float*)Sp)[i] = 0.f;
    __syncthreads();

    for (int pt = 0; pt < 2; ++pt) {
        const int qt = pt ? p : 63 - p;    // heavy tile first (L2 lockstep)
        const int q0 = 32 * qt;
        const int ntile = qt + 1;

        // ---- Q fragments: rows q0+16mt+l15, d = 128w + 32ks + 8lg ----
        bf16x8 qreg[2][4];
#pragma unroll
        for (int mt = 0; mt < 2; ++mt)
#pragma unroll
            for (int ks = 0; ks < 4; ++ks) {
                const float* qp = &out[(bofs + q0 + 16 * mt + l15) * 1024 + 128 * w + 32 * ks + 8 * lg];
                qreg[mt][ks] = cvt8(*reinterpret_cast<const f32x4*>(qp),
                                    *reinterpret_cast<const f32x4*>(qp + 4));
            }

        f32x4 accO[2][8];
#pragma unroll
        for (int mt = 0; mt < 2; ++mt)
#pragma unroll
            for (int nt = 0; nt < 8; ++nt) accO[mt][nt] = (f32x4){0.f, 0.f, 0.f, 0.f};
        float m_run = -INFINITY, l_run = 0.f;

        // ---- prologue: load tile 0 into regs ----
        f32x4 s0[8], s1[8];
        {
            const float* rp = &enc[(bofs + 8 * a) * 1024 + 8 * e];
#pragma unroll
            for (int r = 0; r < 8; ++r) {
                s0[r] = *reinterpret_cast<const f32x4*>(rp + r * 1024);
                s1[r] = *reinterpret_cast<const f32x4*>(rp + r * 1024 + 4);
            }
        }

        for (int tt = 0; tt < ntile; ++tt) {
            // ---- stage write: dual layout from regs ----
#pragma unroll
            for (int r = 0; r < 8; ++r) {
                u32x4 kw;
                kw.x = pk2(s0[r][0], s0[r][1]); kw.y = pk2(s0[r][2], s0[r][3]);
                kw.z = pk2(s1[r][0], s1[r][1]); kw.w = pk2(s1[r][2], s1[r][3]);
                *reinterpret_cast<u32x4*>(Kb + (8 * a + r) * 2064 + 16 * e) = kw;
            }
#pragma unroll
            for (int j = 0; j < 8; ++j) {
                float x0 = (j < 4) ? s0[0][j & 3] : s1[0][j & 3];
                float x1 = (j < 4) ? s0[1][j & 3] : s1[1][j & 3];
                float x2 = (j < 4) ? s0[2][j & 3] : s1[2][j & 3];
                float x3 = (j < 4) ? s0[3][j & 3] : s1[3][j & 3];
                float x4 = (j < 4) ? s0[4][j & 3] : s1[4][j & 3];
                float x5 = (j < 4) ? s0[5][j & 3] : s1[5][j & 3];
                float x6 = (j < 4) ? s0[6][j & 3] : s1[6][j & 3];
                float x7 = (j < 4) ? s0[7][j & 3] : s1[7][j & 3];
                u32x4 vw;
                vw.x = pk2(x0, x1); vw.y = pk2(x2, x3);
                vw.z = pk2(x4, x5); vw.w = pk2(x6, x7);
                *reinterpret_cast<u32x4*>(Vb + (8 * e + j) * 80 + 16 * a) = vw;
            }
            bar_lds();  // B1: staging visible

            // ---- prefetch next tile into (now dead) regs; stays in flight ----
            if (tt + 1 < ntile) {
                const float* rp = &enc[(bofs + 32 * (tt + 1) + 8 * a) * 1024 + 8 * e];
#pragma unroll
                for (int r = 0; r < 8; ++r) {
                    s0[r] = *reinterpret_cast<const f32x4*>(rp + r * 1024);
                    s1[r] = *reinterpret_cast<const f32x4*>(rp + r * 1024 + 4);
                }
            }

            // ---- S phase: wave d-slice 128w, full 32x32 S via LDS atomics ----
            f32x4 accS[2][2];
#pragma unroll
            for (int i = 0; i < 2; ++i)
#pragma unroll
                for (int j = 0; j < 2; ++j) accS[i][j] = (f32x4){0.f, 0.f, 0.f, 0.f};
#pragma unroll
            for (int ks = 0; ks < 4; ++ks) {
                const char* kb = Kb + l15 * 2064 + 16 * (16 * w + 4 * ks + lg);
                bf16x8 k0 = *reinterpret_cast<const bf16x8*>(kb);
                bf16x8 k1 = *reinterpret_cast<const bf16x8*>(kb + 16 * 2064);
                accS[0][0] = MFMA16(qreg[0][ks], k0, accS[0][0]);
                accS[1][0] = MFMA16(qreg[1][ks], k0, accS[1][0]);
                accS[0][1] = MFMA16(qreg[0][ks], k1, accS[0][1]);
                accS[1][1] = MFMA16(qreg[1][ks], k1, accS[1][1]);
            }
#pragma unroll
            for (int mt = 0; mt < 2; ++mt)
#pragma unroll
                for (int nt = 0; nt < 2; ++nt)
#pragma unroll
                    for (int rg = 0; rg < 4; ++rg)
                        atomicAdd(&Sp[16 * mt + 4 * lg + rg][16 * nt + l15], accS[mt][nt][rg]);
            bar_lds();  // B2: partials summed

            // ---- softmax: srow per lane-group, 2 cols per lane ----
            {
                const int c0 = 2 * l15;
                f32x2 s = *reinterpret_cast<f32x2*>(&Sp[srow][c0]);
                const int kvb = 32 * tt;
                if (kvb + c0 + 0 > q0 + srow) s[0] = -1e30f;
                if (kvb + c0 + 1 > q0 + srow) s[1] = -1e30f;
                float mx = fmaxf(s[0], s[1]);
#pragma unroll
                for (int off = 1; off < 16; off <<= 1) mx = fmaxf(mx, __shfl_xor(mx, off));
                float mnew = fmaxf(m_run, mx);
                float al = __expf(m_run - mnew);
                float e0 = __expf(s[0] - mnew), e1 = __expf(s[1] - mnew);
                float ts = e0 + e1;
#pragma unroll
                for (int off = 1; off < 16; off <<= 1) ts += __shfl_xor(ts, off);
                l_run = l_run * al + ts;
                m_run = mnew;
                if (l15 == 0) Avec[srow] = al;
                *reinterpret_cast<unsigned*>(&Pb[srow][c0]) = pk2(e0, e1);
                *reinterpret_cast<f32x2*>(&Sp[srow][c0]) = (f32x2){0.f, 0.f};
            }
            bar_lds();  // B3: P, Avec visible; Sp re-zeroed

            // ---- PV: wave d-slice 128w ----
            float af_[2][4];
#pragma unroll
            for (int mt = 0; mt < 2; ++mt)
#pragma unroll
                for (int rg = 0; rg < 4; ++rg) af_[mt][rg] = Avec[16 * mt + 4 * lg + rg];
#pragma unroll
            for (int mt = 0; mt < 2; ++mt)
#pragma unroll
                for (int nt = 0; nt < 8; ++nt)
#pragma unroll
                    for (int rg = 0; rg < 4; ++rg) accO[mt][nt][rg] *= af_[mt][rg];

            bf16x8 pa[2];
#pragma unroll
            for (int mt = 0; mt < 2; ++mt)
                pa[mt] = *reinterpret_cast<bf16x8*>(
                    (char*)Pb + (16 * mt + l15) * 80 + 16 * lg);
#pragma unroll
            for (int nt = 0; nt < 8; ++nt) {
                const int d = 128 * w + 16 * nt + l15;
                bf16x8 vf = *reinterpret_cast<bf16x8*>(Vb + d * 80 + 16 * lg);
                accO[0][nt] = MFMA16(pa[0], vf, accO[0][nt]);
                accO[1][nt] = MFMA16(pa[1], vf, accO[1][nt]);
            }
            bar_lds();  // B0: all LDS readers done -> next stage may overwrite
        }

        // ---- finalize this q-tile ----
        if (l15 == 0) Linv[srow] = 1.0f / l_run;
        bar_lds();
        float dv[2][4];
#pragma unroll
        for (int mt = 0; mt < 2; ++mt)
#pragma unroll
            for (int rg = 0; rg < 4; ++rg) dv[mt][rg] = Linv[16 * mt + 4 * lg + rg];
#pragma unroll
        for (int mt = 0; mt < 2; ++mt)
#pragma unroll
            for (int nt = 0; nt < 8; ++nt)
#pragma unroll
                for (int rg = 0; rg < 4; ++rg) {
                    size_t row = bofs + q0 + 16 * mt + 4 * lg + rg;
                    int col = 128 * w + 16 * nt + l15;
                    out[row * 1024 + col] = accO[mt][nt][rg] * dv[mt][rg];
                }
        bar_lds();  // Linv reads done before next pt reuses it
    }
}

// ---------------------------------------------------------------------------
extern "C" void kernel_launch(void* const* d_in, const int* in_sizes, int n_in,
                              void* d_out, int out_size, void* d_ws, size_t ws_size,
                              hipStream_t stream)
{
    const float* enc = (const float*)d_in[0];
    const float* R = (const float*)d_in[1];
    float* out = (float*)d_out;

    qr_gemm_kernel<<<dim3(128, 8), 256, 0, stream>>>(enc, R, out);
    attn_kernel<<<dim3(256), 512, 0, stream>>>(enc, out);
}

// Round 5
// 376.782 us; speedup vs baseline: 2.8795x; 2.7467x over previous
//
#include <hip/hip_runtime.h>
#include <hip/hip_bf16.h>

// RelationAttn: out = softmax_causal((enc @ R) @ enc^T) @ enc
// enc: [8,2048,1024] f32, R: [1024,1024] f32, out: [8,2048,1024] f32
//
// Materialized-S pipeline (barrier-light GEMMs, f16 compute):
//   K1: Q = enc @ R           -> d_out (f32)
//   K2: S = Q @ enc^T causal  -> d_ws (f16, 8x2048x2048), lower-tri tiles only
//   K3: P = softmax_row(S)    -> in place over d_ws (f16)
//   K4: O = P @ enc           -> d_out (f32)
// Fallback (ws too small): R3 flash attention kernel.

typedef __attribute__((ext_vector_type(4))) float f32x4;
typedef __attribute__((ext_vector_type(2))) float f32x2;
typedef __attribute__((ext_vector_type(8))) short bf16x8;
typedef __attribute__((ext_vector_type(4))) short short4v;
typedef __attribute__((ext_vector_type(4))) unsigned u32x4;
typedef __attribute__((ext_vector_type(8))) __fp16 f16x8;
typedef __attribute__((ext_vector_type(4))) __fp16 f16x4;
typedef __attribute__((ext_vector_type(2))) __fp16 f16x2;

#define MFMA16H(A, B, C) __builtin_amdgcn_mfma_f32_16x16x32_f16(A, B, C, 0, 0, 0)
#define MFMA16B(A, B, C) __builtin_amdgcn_mfma_f32_16x16x32_bf16(A, B, C, 0, 0, 0)

// ---- f16 helpers ----
__device__ __forceinline__ f16x4 cvt4h(f32x4 a) {
    union { f16x4 v; f16x2 h[2]; } r;
    r.h[0] = __builtin_amdgcn_cvt_pkrtz(a[0], a[1]);
    r.h[1] = __builtin_amdgcn_cvt_pkrtz(a[2], a[3]);
    return r.v;
}

// ---- bf16 helpers (fallback kernel) ----
__device__ __forceinline__ unsigned pk2(float a, float b) {
    return __builtin_amdgcn_perm(__float_as_uint(b), __float_as_uint(a), 0x07060302u);
}
__device__ __forceinline__ bf16x8 cvt8(f32x4 x0, f32x4 x1) {
    union { bf16x8 v; unsigned u[4]; } r;
    r.u[0] = pk2(x0[0], x0[1]); r.u[1] = pk2(x0[2], x0[3]);
    r.u[2] = pk2(x1[0], x1[1]); r.u[3] = pk2(x1[2], x1[3]);
    return r.v;
}
__device__ __forceinline__ void bar_lds() {
    asm volatile("s_waitcnt lgkmcnt(0)" ::: "memory");
    __builtin_amdgcn_s_barrier();
    asm volatile("" ::: "memory");
}

// ---------------------------------------------------------------------------
// K1: Q = enc(16384x1024) @ R(1024x1024), 128x128 tile, 4 waves, f16 MFMA
// ---------------------------------------------------------------------------
__global__ __launch_bounds__(256) void qr_gemm_kernel(
    const float* __restrict__ A, const float* __restrict__ B, float* C)
{
    __shared__ __align__(16) char sA[128 * 64];
    __shared__ __align__(16) char sB[128 * 64];
    const int t = threadIdx.x;
    const int w = t >> 6, l = t & 63;
    const int l15 = l & 15, lg = l >> 4;
    const int bm = blockIdx.x * 128;
    const int bn = blockIdx.y * 128;

    f32x4 acc[4][4];
#pragma unroll
    for (int i = 0; i < 4; ++i)
#pragma unroll
        for (int j = 0; j < 4; ++j) acc[i][j] = (f32x4){0.f, 0.f, 0.f, 0.f};

    const int kq = 4 * (t & 7);
    const int i2 = t >> 3;

    for (int kk = 0; kk < 1024; kk += 32) {
#pragma unroll
        for (int it = 0; it < 4; ++it) {
            int m = i2 + 32 * it;
            f32x4 x = *reinterpret_cast<const f32x4*>(&A[(size_t)(bm + m) * 1024 + kk + kq]);
            *reinterpret_cast<f16x4*>(sA + m * 64 + ((2 * kq) ^ (((m >> 1) & 3) << 4))) = cvt4h(x);
        }
        {
            int n0 = 4 * i2;
            f32x4 x[4];
#pragma unroll
            for (int r = 0; r < 4; ++r)
                x[r] = *reinterpret_cast<const f32x4*>(&B[(size_t)(kk + kq + r) * 1024 + bn + n0]);
#pragma unroll
            for (int j = 0; j < 4; ++j) {
                int n = n0 + j;
                union { f16x4 v; f16x2 h[2]; } s;
                s.h[0] = __builtin_amdgcn_cvt_pkrtz(x[0][j], x[1][j]);
                s.h[1] = __builtin_amdgcn_cvt_pkrtz(x[2][j], x[3][j]);
                *reinterpret_cast<f16x4*>(sB + n * 64 + ((2 * kq) ^ (((n >> 1) & 3) << 4))) = s.v;
            }
        }
        __syncthreads();
        const int r0 = (w >> 1) * 64, c0 = (w & 1) * 64;
        f16x8 af[4], bfv[4];
#pragma unroll
        for (int mt = 0; mt < 4; ++mt) {
            int m = r0 + 16 * mt + l15;
            af[mt] = *reinterpret_cast<f16x8*>(sA + m * 64 + ((16 * lg) ^ (((m >> 1) & 3) << 4)));
        }
#pragma unroll
        for (int nt = 0; nt < 4; ++nt) {
            int n = c0 + 16 * nt + l15;
            bfv[nt] = *reinterpret_cast<f16x8*>(sB + n * 64 + ((16 * lg) ^ (((n >> 1) & 3) << 4)));
        }
#pragma unroll
        for (int mt = 0; mt < 4; ++mt)
#pragma unroll
            for (int nt = 0; nt < 4; ++nt)
                acc[mt][nt] = MFMA16H(af[mt], bfv[nt], acc[mt][nt]);
        __syncthreads();
    }
#pragma unroll
    for (int mt = 0; mt < 4; ++mt)
#pragma unroll
        for (int nt = 0; nt < 4; ++nt)
#pragma unroll
            for (int rg = 0; rg < 4; ++rg) {
                int row = bm + (w >> 1) * 64 + 16 * mt + 4 * lg + rg;
                int col = bn + (w & 1) * 64 + 16 * nt + l15;
                C[(size_t)row * 1024 + col] = acc[mt][nt][rg];
            }
}

// ---------------------------------------------------------------------------
// K2: S = Q @ enc^T (causal, lower-tri 128x128 tiles), S f16 -> ws
// Both operands row-major k-contig (B^T GEMM). 4 waves.
// ---------------------------------------------------------------------------
__global__ __launch_bounds__(256) void s_gemm_kernel(
    const float* __restrict__ Q, const float* __restrict__ enc, __fp16* __restrict__ S)
{
    __shared__ __align__(16) char sA[128 * 64];
    __shared__ __align__(16) char sB[128 * 64];
    const int t = threadIdx.x;
    const int w = t >> 6, l = t & 63;
    const int l15 = l & 15, lg = l >> 4;

    // heavy-first lower-tri tile mapping
    int tau = 135 - (int)blockIdx.x;
    int qt = 0, rem = tau;
    while (rem > qt) { rem -= (qt + 1); qt += 1; }
    const int kt = rem;
    const int b = blockIdx.y;
    const int bm = qt * 128, bn = kt * 128;
    const float* Arow = Q + ((size_t)b * 2048 + bm) * 1024;
    const float* Brow = enc + ((size_t)b * 2048 + bn) * 1024;

    f32x4 acc[4][4];
#pragma unroll
    for (int i = 0; i < 4; ++i)
#pragma unroll
        for (int j = 0; j < 4; ++j) acc[i][j] = (f32x4){0.f, 0.f, 0.f, 0.f};

    const int kq = 4 * (t & 7);
    const int i2 = t >> 3;

    for (int kk = 0; kk < 1024; kk += 32) {
#pragma unroll
        for (int it = 0; it < 4; ++it) {
            int m = i2 + 32 * it;
            int sw = (2 * kq) ^ (((m >> 1) & 3) << 4);
            f32x4 xa = *reinterpret_cast<const f32x4*>(&Arow[(size_t)m * 1024 + kk + kq]);
            f32x4 xb = *reinterpret_cast<const f32x4*>(&Brow[(size_t)m * 1024 + kk + kq]);
            *reinterpret_cast<f16x4*>(sA + m * 64 + sw) = cvt4h(xa);
            *reinterpret_cast<f16x4*>(sB + m * 64 + sw) = cvt4h(xb);
        }
        __syncthreads();
        const int r0 = (w >> 1) * 64, c0 = (w & 1) * 64;
        f16x8 af[4], bfv[4];
#pragma unroll
        for (int mt = 0; mt < 4; ++mt) {
            int m = r0 + 16 * mt + l15;
            af[mt] = *reinterpret_cast<f16x8*>(sA + m * 64 + ((16 * lg) ^ (((m >> 1) & 3) << 4)));
        }
#pragma unroll
        for (int nt = 0; nt < 4; ++nt) {
            int n = c0 + 16 * nt + l15;
            bfv[nt] = *reinterpret_cast<f16x8*>(sB + n * 64 + ((16 * lg) ^ (((n >> 1) & 3) << 4)));
        }
#pragma unroll
        for (int mt = 0; mt < 4; ++mt)
#pragma unroll
            for (int nt = 0; nt < 4; ++nt)
                acc[mt][nt] = MFMA16H(af[mt], bfv[nt], acc[mt][nt]);
        __syncthreads();
    }
    const int r0 = (w >> 1) * 64, c0 = (w & 1) * 64;
#pragma unroll
    for (int mt = 0; mt < 4; ++mt)
#pragma unroll
        for (int nt = 0; nt < 4; ++nt)
#pragma unroll
            for (int rg = 0; rg < 4; ++rg) {
                int rt = r0 + 16 * mt + 4 * lg + rg;
                int ct = c0 + 16 * nt + l15;
                float v = acc[mt][nt][rg];
                if (kt == qt && ct > rt) v = -30000.f;
                S[((size_t)b * 2048 + bm + rt) * 2048 + bn + ct] = (__fp16)v;
            }
}

// ---------------------------------------------------------------------------
// K3: in-place row softmax over S (f16). One wave per row; L = roundup(r+1,128).
// ---------------------------------------------------------------------------
__global__ __launch_bounds__(256) void softmax_kernel(__fp16* __restrict__ S)
{
    const int t = threadIdx.x;
    const int wv = t >> 6, l = t & 63;
    const int r = blockIdx.x * 4 + wv;
    const int b = blockIdx.y;
    __fp16* row = S + ((size_t)b * 2048 + r) * 2048;
    const int L = ((r >> 7) + 1) << 7;

    float v[4][8];
    float mx = -1e30f;
#pragma unroll
    for (int i = 0; i < 4; ++i) {
        int c0 = 8 * l + 512 * i;
        if (c0 < L) {
            f16x8 h = *reinterpret_cast<const f16x8*>(row + c0);
#pragma unroll
            for (int j = 0; j < 8; ++j) { v[i][j] = (float)h[j]; mx = fmaxf(mx, v[i][j]); }
        } else {
#pragma unroll
            for (int j = 0; j < 8; ++j) v[i][j] = -1e30f;
        }
    }
#pragma unroll
    for (int off = 1; off < 64; off <<= 1) mx = fmaxf(mx, __shfl_xor(mx, off));
    float sm = 0.f;
#pragma unroll
    for (int i = 0; i < 4; ++i)
#pragma unroll
        for (int j = 0; j < 8; ++j) { v[i][j] = __expf(v[i][j] - mx); sm += v[i][j]; }
#pragma unroll
    for (int off = 1; off < 64; off <<= 1) sm += __shfl_xor(sm, off);
    const float inv = 1.f / sm;
#pragma unroll
    for (int i = 0; i < 4; ++i) {
        int c0 = 8 * l + 512 * i;
        if (c0 < L) {
            union { f16x8 v8; f16x2 h[4]; } o;
#pragma unroll
            for (int j = 0; j < 4; ++j)
                o.h[j] = __builtin_amdgcn_cvt_pkrtz(v[i][2 * j] * inv, v[i][2 * j + 1] * inv);
            *reinterpret_cast<f16x8*>(row + c0) = o.v8;
        }
    }
}

// ---------------------------------------------------------------------------
// K4: O = P @ enc. Block = 128q x 128d, 8 waves (2q x 4d), KVB=64 per step.
// ---------------------------------------------------------------------------
__global__ __launch_bounds__(512) void pv_gemm_kernel(
    const __fp16* __restrict__ P, const float* __restrict__ enc, float* __restrict__ out)
{
    __shared__ __align__(16) char sA[128 * 128];  // P[q][kv64] f16, XOR-swizzled
    __shared__ __align__(16) char sB[128 * 128];  // enc^T[d][kv64] f16, XOR-swizzled
    const int t = threadIdx.x;
    const int w = t >> 6, l = t & 63;
    const int l15 = l & 15, lg = (l >> 4) & 3;
    const int wq = w >> 2, wdv = w & 3;
    const int qtb = 15 - (int)blockIdx.x;  // heavy first
    const int dblk = blockIdx.y;
    const int b = blockIdx.z;
    const int q0 = 128 * qtb;
    const int nkv = 128 * (qtb + 1);
    const __fp16* Pbase = P + ((size_t)b * 2048 + q0) * 2048;
    const float* Eb = enc + (size_t)b * 2048 * 1024;

    f32x4 acc[4][2];
#pragma unroll
    for (int i = 0; i < 4; ++i)
#pragma unroll
        for (int j = 0; j < 2; ++j) acc[i][j] = (f32x4){0.f, 0.f, 0.f, 0.f};

    const int ar = t >> 2, aseg = t & 3;   // A staging: row, 16-f16 segment
    const int ba = t >> 5, bdq = t & 31;   // B staging: kv-quartet group, d-quartet

    for (int kv0 = 0; kv0 < nkv; kv0 += 64) {
        __syncthreads();  // previous step's readers done
        // stage A: P[q0+ar][kv0 + 16*aseg .. +15]
        {
            const __fp16* src = Pbase + (size_t)ar * 2048 + kv0 + 16 * aseg;
            u32x4 v0 = *reinterpret_cast<const u32x4*>(src);
            u32x4 v1 = *reinterpret_cast<const u32x4*>(src + 8);
            const int sw = (ar & 7) << 4;
            *reinterpret_cast<u32x4*>(sA + ar * 128 + ((32 * aseg) ^ sw)) = v0;
            *reinterpret_cast<u32x4*>(sA + ar * 128 + ((32 * aseg + 16) ^ sw)) = v1;
        }
        // stage B: enc rows kv0+4ba..+3, cols 128*dblk + 4*bdq..+3 -> sB[d][kv]
        {
            const float* src = Eb + (size_t)(kv0 + 4 * ba) * 1024 + 128 * dblk + 4 * bdq;
            f32x4 x0 = *reinterpret_cast<const f32x4*>(src);
            f32x4 x1 = *reinterpret_cast<const f32x4*>(src + 1024);
            f32x4 x2 = *reinterpret_cast<const f32x4*>(src + 2048);
            f32x4 x3 = *reinterpret_cast<const f32x4*>(src + 3072);
#pragma unroll
            for (int j = 0; j < 4; ++j) {
                int d = 4 * bdq + j;
                union { f16x4 v; f16x2 h[2]; } s;
                s.h[0] = __builtin_amdgcn_cvt_pkrtz(x0[j], x1[j]);
                s.h[1] = __builtin_amdgcn_cvt_pkrtz(x2[j], x3[j]);
                *reinterpret_cast<f16x4*>(sB + d * 128 + ((8 * ba) ^ ((d & 7) << 4))) = s.v;
            }
        }
        __syncthreads();
        // compute: 2 k-steps of 32
#pragma unroll
        for (int ks = 0; ks < 2; ++ks) {
            f16x8 afr[4], bfr[2];
#pragma unroll
            for (int mt = 0; mt < 4; ++mt) {
                int rr = 64 * wq + 16 * mt + l15;
                afr[mt] = *reinterpret_cast<f16x8*>(sA + rr * 128 + ((64 * ks + 16 * lg) ^ ((rr & 7) << 4)));
            }
#pragma unroll
            for (int nt = 0; nt < 2; ++nt) {
                int d = 32 * wdv + 16 * nt + l15;
                bfr[nt] = *reinterpret_cast<f16x8*>(sB + d * 128 + ((64 * ks + 16 * lg) ^ ((d & 7) << 4)));
            }
#pragma unroll
            for (int mt = 0; mt < 4; ++mt)
#pragma unroll
                for (int nt = 0; nt < 2; ++nt)
                    acc[mt][nt] = MFMA16H(afr[mt], bfr[nt], acc[mt][nt]);
        }
    }
#pragma unroll
    for (int mt = 0; mt < 4; ++mt)
#pragma unroll
        for (int nt = 0; nt < 2; ++nt)
#pragma unroll
            for (int rg = 0; rg < 4; ++rg) {
                size_t row = (size_t)b * 2048 + q0 + 64 * wq + 16 * mt + 4 * lg + rg;
                int col = 128 * dblk + 32 * wdv + 16 * nt + l15;
                out[row * 1024 + col] = acc[mt][nt][rg];
            }
}

// ---------------------------------------------------------------------------
// Fallback: R3 flash attention (used only if ws too small for S).
// ---------------------------------------------------------------------------
__global__ __launch_bounds__(512, 2) void attn_kernel(
    const float* __restrict__ enc, float* __restrict__ out)
{
    __shared__ __align__(16) char Kb[32 * 2064];
    __shared__ __align__(16) char Vb[1024 * 80];
    __shared__ float Sp[32][34];
    __shared__ unsigned short Pb[32][40];
    __shared__ float Avec[32];
    __shared__ float Linv[32];

    const int t = threadIdx.x;
    const int w = t >> 6, l = t & 63;
    const int l15 = l & 15, lg = (l >> 4) & 3;
    const int srow = 4 * w + lg;

    const int b = blockIdx.x & 7;
    const int p = blockIdx.x >> 3;
    const size_t bofs = (size_t)b * 2048;

    const int a = t & 3;
    const int e = t >> 2;

    for (int i = t; i < 32 * 34; i += 512) ((float*)Sp)[i] = 0.f;
    __syncthreads();

    for (int pt = 0; pt < 2; ++pt) {
        const int qt = pt ? p : 63 - p;
        const int q0 = 32 * qt;
        const int ntile = qt + 1;

        bf16x8 qreg[2][4];
#pragma unroll
        for (int mt = 0; mt < 2; ++mt)
#pragma unroll
            for (int ks = 0; ks < 4; ++ks) {
                const float* qp = &out[(bofs + q0 + 16 * mt + l15) * 1024 + 128 * w + 32 * ks + 8 * lg];
                qreg[mt][ks] = cvt8(*reinterpret_cast<const f32x4*>(qp),
                                    *reinterpret_cast<const f32x4*>(qp + 4));
            }

        f32x4 accO[2][8];
#pragma unroll
        for (int mt = 0; mt < 2; ++mt)
#pragma unroll
            for (int nt = 0; nt < 8; ++nt) accO[mt][nt] = (f32x4){0.f, 0.f, 0.f, 0.f};
        float m_run = -INFINITY, l_run = 0.f;

        f32x4 s0[8], s1[8];
        {
            const float* rp = &enc[(bofs + 8 * a) * 1024 + 8 * e];
#pragma unroll
            for (int r = 0; r < 8; ++r) {
                s0[r] = *reinterpret_cast<const f32x4*>(rp + r * 1024);
                s1[r] = *reinterpret_cast<const f32x4*>(rp + r * 1024 + 4);
            }
        }

        for (int tt = 0; tt < ntile; ++tt) {
#pragma unroll
            for (int r = 0; r < 8; ++r) {
                u32x4 kw;
                kw.x = pk2(s0[r][0], s0[r][1]); kw.y = pk2(s0[r][2], s0[r][3]);
                kw.z = pk2(s1[r][0], s1[r][1]); kw.w = pk2(s1[r][2], s1[r][3]);
                *reinterpret_cast<u32x4*>(Kb + (8 * a + r) * 2064 + 16 * e) = kw;
            }
#pragma unroll
            for (int j = 0; j < 8; ++j) {
                float x0 = (j < 4) ? s0[0][j & 3] : s1[0][j & 3];
                float x1 = (j < 4) ? s0[1][j & 3] : s1[1][j & 3];
                float x2 = (j < 4) ? s0[2][j & 3] : s1[2][j & 3];
                float x3 = (j < 4) ? s0[3][j & 3] : s1[3][j & 3];
                float x4 = (j < 4) ? s0[4][j & 3] : s1[4][j & 3];
                float x5 = (j < 4) ? s0[5][j & 3] : s1[5][j & 3];
                float x6 = (j < 4) ? s0[6][j & 3] : s1[6][j & 3];
                float x7 = (j < 4) ? s0[7][j & 3] : s1[7][j & 3];
                u32x4 vw;
                vw.x = pk2(x0, x1); vw.y = pk2(x2, x3);
                vw.z = pk2(x4, x5); vw.w = pk2(x6, x7);
                *reinterpret_cast<u32x4*>(Vb + (8 * e + j) * 80 + 16 * a) = vw;
            }
            bar_lds();

            if (tt + 1 < ntile) {
                const float* rp = &enc[(bofs + 32 * (tt + 1) + 8 * a) * 1024 + 8 * e];
#pragma unroll
                for (int r = 0; r < 8; ++r) {
                    s0[r] = *reinterpret_cast<const f32x4*>(rp + r * 1024);
                    s1[r] = *reinterpret_cast<const f32x4*>(rp + r * 1024 + 4);
                }
            }

            f32x4 accS[2][2];
#pragma unroll
            for (int i = 0; i < 2; ++i)
#pragma unroll
                for (int j = 0; j < 2; ++j) accS[i][j] = (f32x4){0.f, 0.f, 0.f, 0.f};
#pragma unroll
            for (int ks = 0; ks < 4; ++ks) {
                const char* kb = Kb + l15 * 2064 + 16 * (16 * w + 4 * ks + lg);
                bf16x8 k0 = *reinterpret_cast<const bf16x8*>(kb);
                bf16x8 k1 = *reinterpret_cast<const bf16x8*>(kb + 16 * 2064);
                accS[0][0] = MFMA16B(qreg[0][ks], k0, accS[0][0]);
                accS[1][0] = MFMA16B(qreg[1][ks], k0, accS[1][0]);
                accS[0][1] = MFMA16B(qreg[0][ks], k1, accS[0][1]);
                accS[1][1] = MFMA16B(qreg[1][ks], k1, accS[1][1]);
            }
#pragma unroll
            for (int mt = 0; mt < 2; ++mt)
#pragma unroll
                for (int nt = 0; nt < 2; ++nt)
#pragma unroll
                    for (int rg = 0; rg < 4; ++rg)
                        atomicAdd(&Sp[16 * mt + 4 * lg + rg][16 * nt + l15], accS[mt][nt][rg]);
            bar_lds();

            {
                const int c0 = 2 * l15;
                f32x2 s = *reinterpret_cast<f32x2*>(&Sp[srow][c0]);
                const int kvb = 32 * tt;
                if (kvb + c0 + 0 > q0 + srow) s[0] = -1e30f;
                if (kvb + c0 + 1 > q0 + srow) s[1] = -1e30f;
                float mx = fmaxf(s[0], s[1]);
#pragma unroll
                for (int off = 1; off < 16; off <<= 1) mx = fmaxf(mx, __shfl_xor(mx, off));
                float mnew = fmaxf(m_run, mx);
                float al = __expf(m_run - mnew);
                float e0 = __expf(s[0] - mnew), e1 = __expf(s[1] - mnew);
                float ts = e0 + e1;
#pragma unroll
                for (int off = 1; off < 16; off <<= 1) ts += __shfl_xor(ts, off);
                l_run = l_run * al + ts;
                m_run = mnew;
                if (l15 == 0) Avec[srow] = al;
                *reinterpret_cast<unsigned*>(&Pb[srow][c0]) = pk2(e0, e1);
                *reinterpret_cast<f32x2*>(&Sp[srow][c0]) = (f32x2){0.f, 0.f};
            }
            bar_lds();

            float af_[2][4];
#pragma unroll
            for (int mt = 0; mt < 2; ++mt)
#pragma unroll
                for (int rg = 0; rg < 4; ++rg) af_[mt][rg] = Avec[16 * mt + 4 * lg + rg];
#pragma unroll
            for (int mt = 0; mt < 2; ++mt)
#pragma unroll
                for (int nt = 0; nt < 8; ++nt)
#pragma unroll
                    for (int rg = 0; rg < 4; ++rg) accO[mt][nt][rg] *= af_[mt][rg];

            bf16x8 pa[2];
#pragma unroll
            for (int mt = 0; mt < 2; ++mt)
                pa[mt] = *reinterpret_cast<bf16x8*>(
                    (char*)Pb + (16 * mt + l15) * 80 + 16 * lg);
#pragma unroll
            for (int nt = 0; nt < 8; ++nt) {
                const int d = 128 * w + 16 * nt + l15;
                bf16x8 vf = *reinterpret_cast<bf16x8*>(Vb + d * 80 + 16 * lg);
                accO[0][nt] = MFMA16B(pa[0], vf, accO[0][nt]);
                accO[1][nt] = MFMA16B(pa[1], vf, accO[1][nt]);
            }
            bar_lds();
        }

        if (l15 == 0) Linv[srow] = 1.0f / l_run;
        bar_lds();
        float dv[2][4];
#pragma unroll
        for (int mt = 0; mt < 2; ++mt)
#pragma unroll
            for (int rg = 0; rg < 4; ++rg) dv[mt][rg] = Linv[16 * mt + 4 * lg + rg];
#pragma unroll
        for (int mt = 0; mt < 2; ++mt)
#pragma unroll
            for (int nt = 0; nt < 8; ++nt)
#pragma unroll
                for (int rg = 0; rg < 4; ++rg) {
                    size_t row = bofs + q0 + 16 * mt + 4 * lg + rg;
                    int col = 128 * w + 16 * nt + l15;
                    out[row * 1024 + col] = accO[mt][nt][rg] * dv[mt][rg];
                }
        bar_lds();
    }
}

// ---------------------------------------------------------------------------
extern "C" void kernel_launch(void* const* d_in, const int* in_sizes, int n_in,
                              void* d_out, int out_size, void* d_ws, size_t ws_size,
                              hipStream_t stream)
{
    const float* enc = (const float*)d_in[0];
    const float* R = (const float*)d_in[1];
    float* out = (float*)d_out;

    // K1: Q = enc @ R -> d_out
    qr_gemm_kernel<<<dim3(128, 8), 256, 0, stream>>>(enc, R, out);

    const size_t need = (size_t)8 * 2048 * 2048 * sizeof(__fp16);
    if (ws_size >= need) {
        __fp16* S = (__fp16*)d_ws;
        s_gemm_kernel<<<dim3(136, 8), 256, 0, stream>>>(out, enc, S);
        softmax_kernel<<<dim3(512, 8), 256, 0, stream>>>(S);
        pv_gemm_kernel<<<dim3(16, 8, 8), 512, 0, stream>>>(S, enc, out);
    } else {
        attn_kernel<<<dim3(256), 512, 0, stream>>>(enc, out);
    }
}

// Round 6
// 218.928 us; speedup vs baseline: 4.9558x; 1.7210x over previous
//
#include <hip/hip_runtime.h>
#include <hip/hip_bf16.h>

// RelationAttn: out = softmax_causal((enc @ R) @ enc^T) @ enc
// enc: [8,2048,1024] f32, R: [1024,1024] f32, out: [8,2048,1024] f32
//
// f16 pipeline, all GEMMs m97-style (global_load_lds width-16, BK=64, 128^2):
//   P0: enc -> enc_h (f16, d_out upper 32MB) + enc_t (f16 transposed, ws)
//   P1: R   -> R_t (f16 transposed, ws)
//   K1: Q_h = enc_h @ R_t^T      -> d_out lower 32MB (f16)
//   K2: S = Q_h @ enc_h^T causal -> ws (f16, lower-tri 128^2 tiles)
//   K3: P = softmax_row(S) in place
//   K4: out = P @ enc_t^T        -> d_out (f32, overwrites Q_h/enc_h)
// Fallback (ws < 98MB): R5 pipeline (f32-staged GEMMs).

typedef __attribute__((ext_vector_type(4))) float f32x4;
typedef __attribute__((ext_vector_type(4))) unsigned u32x4;
typedef __attribute__((ext_vector_type(8))) __fp16 f16x8;
typedef __attribute__((ext_vector_type(4))) __fp16 f16x4;
typedef __attribute__((ext_vector_type(2))) __fp16 f16x2;

#define MFMA16H(A, B, C) __builtin_amdgcn_mfma_f32_16x16x32_f16(A, B, C, 0, 0, 0)

__device__ __forceinline__ f16x4 cvt4h(f32x4 a) {
    union { f16x4 v; f16x2 h[2]; } r;
    r.h[0] = __builtin_amdgcn_cvt_pkrtz(a[0], a[1]);
    r.h[1] = __builtin_amdgcn_cvt_pkrtz(a[2], a[3]);
    return r.v;
}

// async global->LDS, 16B per lane; lds dest = wave-uniform base + lane*16
__device__ __forceinline__ void gload16(const void* g, void* l) {
    __builtin_amdgcn_global_load_lds(
        (const __attribute__((address_space(1))) unsigned*)g,
        (__attribute__((address_space(3))) unsigned*)l, 16, 0, 0);
}

// ---------------------------------------------------------------------------
// P0/P1: transpose + convert. src f32 [bz][R][C] -> dstT f16 [bz][C][R]
// and (if dstH) dstH f16 [bz][R][C]. 64x64 tiles, swizzled LDS.
// ---------------------------------------------------------------------------
__global__ __launch_bounds__(256) void transpose_cvt_kernel(
    const float* __restrict__ src, __fp16* __restrict__ dstT,
    __fp16* __restrict__ dstH, int R, int C)
{
    __shared__ __align__(16) char lt[64 * 128];  // [r][c] f16, XOR-swizzled
    const int t = threadIdx.x;
    const int bz = blockIdx.z;
    const int r0 = blockIdx.x * 64, c0 = blockIdx.y * 64;
    const size_t so = (size_t)bz * R * C;
    const int tr = t >> 4;
    const int tc4 = (t & 15) * 4;
#pragma unroll
    for (int p = 0; p < 4; ++p) {
        int rl = tr + 16 * p;
        f32x4 x = *(const f32x4*)(src + so + (size_t)(r0 + rl) * C + c0 + tc4);
        f16x4 h = cvt4h(x);
        if (dstH) *(f16x4*)(dstH + so + (size_t)(r0 + rl) * C + c0 + tc4) = h;
        *(f16x4*)(lt + rl * 128 + ((tc4 * 2) ^ ((rl & 7) << 4))) = h;
    }
    __syncthreads();
#pragma unroll
    for (int p = 0; p < 4; ++p) {
        int dl = tr + 16 * p;
#pragma unroll
        for (int j = 0; j < 4; ++j) {
            int kl = (t & 15) + 16 * j;
            __fp16 v = *(const __fp16*)(lt + kl * 128 + ((dl * 2) ^ ((kl & 7) << 4)));
            dstT[so + (size_t)(c0 + dl) * R + r0 + kl] = v;
        }
    }
}

// ---------------------------------------------------------------------------
// Unified f16 GEMM core: C(128x128) = A(128xK) @ B(128xK)^T, m97 structure.
// CMODE: 0 = f16 out; 1 = f16 out + causal diag mask; 2 = f32 out.
// A,B already offset to tile row 0; Cptr already offset to tile (0,0).
// ---------------------------------------------------------------------------
template <int CMODE>
__device__ __forceinline__ void gemm_core(
    const __fp16* __restrict__ A, const __fp16* __restrict__ B,
    char* __restrict__ Cptr, int ldA, int ldB, int ldC, int K, bool diag)
{
    __shared__ __align__(16) char sA[128 * 128];  // 128 rows x 64 f16 (16KB)
    __shared__ __align__(16) char sB[128 * 128];
    const int t = threadIdx.x;
    const int w = t >> 6, l = t & 63;
    const int l15 = l & 15, lg = l >> 4;
    const int r0 = (w >> 1) * 64, c0 = (w & 1) * 64;

    f32x4 acc[4][4];
#pragma unroll
    for (int i = 0; i < 4; ++i)
#pragma unroll
        for (int j = 0; j < 4; ++j) acc[i][j] = (f32x4){0.f, 0.f, 0.f, 0.f};

    // staging: wave w covers rows 32w..32w+31; instr i rows 32w+8i..+7;
    // lane l: row += l>>3, 16B granule l&7. LDS linear: lane*16 within 1KB chunk.
    const int strow = 32 * w + (l >> 3);
    const __fp16* pa = A + (size_t)strow * ldA + (l & 7) * 8;
    const __fp16* pb = B + (size_t)strow * ldB + (l & 7) * 8;

    for (int kk = 0; kk < K; kk += 64) {
        __syncthreads();  // prev compute done reading LDS
#pragma unroll
        for (int i = 0; i < 4; ++i) {
            gload16(pa + (size_t)(8 * i) * ldA + kk, sA + w * 4096 + i * 1024);
            gload16(pb + (size_t)(8 * i) * ldB + kk, sB + w * 4096 + i * 1024);
        }
        __syncthreads();  // drains vmcnt before barrier -> staging visible
#pragma unroll
        for (int ks = 0; ks < 2; ++ks) {
            f16x8 af[4], bf[4];
#pragma unroll
            for (int mt = 0; mt < 4; ++mt)
                af[mt] = *(const f16x8*)(sA + (r0 + 16 * mt + l15) * 128 + (32 * ks + 8 * lg) * 2);
#pragma unroll
            for (int nt = 0; nt < 4; ++nt)
                bf[nt] = *(const f16x8*)(sB + (c0 + 16 * nt + l15) * 128 + (32 * ks + 8 * lg) * 2);
#pragma unroll
            for (int mt = 0; mt < 4; ++mt)
#pragma unroll
                for (int nt = 0; nt < 4; ++nt)
                    acc[mt][nt] = MFMA16H(af[mt], bf[nt], acc[mt][nt]);
        }
    }
    // C/D layout: col = l15, row = 4*lg + rg (verified in R1-R5)
#pragma unroll
    for (int mt = 0; mt < 4; ++mt)
#pragma unroll
        for (int nt = 0; nt < 4; ++nt)
#pragma unroll
            for (int rg = 0; rg < 4; ++rg) {
                int rr = r0 + 16 * mt + 4 * lg + rg;
                int cc = c0 + 16 * nt + l15;
                float v = acc[mt][nt][rg];
                if (CMODE == 2) {
                    *(float*)(Cptr + ((size_t)rr * ldC + cc) * 4) = v;
                } else {
                    if (CMODE == 1 && diag && cc > rr) v = -30000.f;
                    *(__fp16*)(Cptr + ((size_t)rr * ldC + cc) * 2) = (__fp16)v;
                }
            }
}

// K1: Q_h = enc_h @ R_t^T  (16384x1024 @ 1024x1024)
__global__ __launch_bounds__(256) void gemm_qr(
    const __fp16* __restrict__ encH, const __fp16* __restrict__ Rt,
    __fp16* __restrict__ Qh)
{
    const int bm = ((int)blockIdx.x >> 3) * 128;
    const int bn = ((int)blockIdx.x & 7) * 128;
    gemm_core<0>(encH + (size_t)bm * 1024, Rt + (size_t)bn * 1024,
                 (char*)(Qh + (size_t)bm * 1024 + bn), 1024, 1024, 1024, 1024, false);
}

// K2: S = Q_h @ enc_h^T, causal lower-tri tiles. batch = bid&7 (XCD affinity).
__global__ __launch_bounds__(256) void gemm_s(
    const __fp16* __restrict__ Qh, const __fp16* __restrict__ encH,
    __fp16* __restrict__ S)
{
    const int b = (int)blockIdx.x & 7;
    int rem = 135 - ((int)blockIdx.x >> 3);
    int qt = 0;
    while (rem > qt) { rem -= qt + 1; ++qt; }
    const int kt = rem;
    const size_t bo = (size_t)b * 2048 * 1024;
    const size_t so = (size_t)b * 2048 * 2048;
    gemm_core<1>(Qh + bo + (size_t)(qt * 128) * 1024,
                 encH + bo + (size_t)(kt * 128) * 1024,
                 (char*)(S + so + (size_t)(qt * 128) * 2048 + kt * 128),
                 1024, 1024, 2048, 1024, qt == kt);
}

// K4: out = P @ enc_t^T. Variable K = 128*(qtb+1), heavy-first.
__global__ __launch_bounds__(256) void gemm_pv(
    const __fp16* __restrict__ P, const __fp16* __restrict__ encT,
    float* __restrict__ out)
{
    const int b = (int)blockIdx.x & 7;
    const int r = (int)blockIdx.x >> 3;      // 0..127
    const int qtb = 15 - (r >> 3);
    const int dblk = r & 7;
    const size_t so = (size_t)b * 2048 * 2048;
    const size_t to = (size_t)b * 1024 * 2048;
    const int K = 128 * (qtb + 1);
    gemm_core<2>(P + so + (size_t)(qtb * 128) * 2048,
                 encT + to + (size_t)(dblk * 128) * 2048,
                 (char*)(out + (size_t)b * 2048 * 1024 + (size_t)(qtb * 128) * 1024 + dblk * 128),
                 2048, 2048, 1024, K, false);
}

// ---------------------------------------------------------------------------
// K3: in-place row softmax over S (f16). One wave per row; L = roundup(r+1,128).
// ---------------------------------------------------------------------------
__global__ __launch_bounds__(256) void softmax_kernel(__fp16* __restrict__ S)
{
    const int t = threadIdx.x;
    const int wv = t >> 6, l = t & 63;
    const int r = blockIdx.x * 4 + wv;
    const int b = blockIdx.y;
    __fp16* row = S + ((size_t)b * 2048 + r) * 2048;
    const int L = ((r >> 7) + 1) << 7;

    float v[4][8];
    float mx = -1e30f;
#pragma unroll
    for (int i = 0; i < 4; ++i) {
        int c0 = 8 * l + 512 * i;
        if (c0 < L) {
            f16x8 h = *reinterpret_cast<const f16x8*>(row + c0);
#pragma unroll
            for (int j = 0; j < 8; ++j) { v[i][j] = (float)h[j]; mx = fmaxf(mx, v[i][j]); }
        } else {
#pragma unroll
            for (int j = 0; j < 8; ++j) v[i][j] = -1e30f;
        }
    }
#pragma unroll
    for (int off = 1; off < 64; off <<= 1) mx = fmaxf(mx, __shfl_xor(mx, off));
    float sm = 0.f;
#pragma unroll
    for (int i = 0; i < 4; ++i)
#pragma unroll
        for (int j = 0; j < 8; ++j) { v[i][j] = __expf(v[i][j] - mx); sm += v[i][j]; }
#pragma unroll
    for (int off = 1; off < 64; off <<= 1) sm += __shfl_xor(sm, off);
    const float inv = 1.f / sm;
#pragma unroll
    for (int i = 0; i < 4; ++i) {
        int c0 = 8 * l + 512 * i;
        if (c0 < L) {
            union { f16x8 v8; f16x2 h[4]; } o;
#pragma unroll
            for (int j = 0; j < 4; ++j)
                o.h[j] = __builtin_amdgcn_cvt_pkrtz(v[i][2 * j] * inv, v[i][2 * j + 1] * inv);
            *reinterpret_cast<f16x8*>(row + c0) = o.v8;
        }
    }
}

// ===========================================================================
// Fallback path (R5): f32-staged GEMMs, used only if ws < 98MB.
// ===========================================================================
__global__ __launch_bounds__(256) void qr_gemm_kernel(
    const float* __restrict__ A, const float* __restrict__ B, float* C)
{
    __shared__ __align__(16) char sA[128 * 64];
    __shared__ __align__(16) char sB[128 * 64];
    const int t = threadIdx.x;
    const int w = t >> 6, l = t & 63;
    const int l15 = l & 15, lg = l >> 4;
    const int bm = blockIdx.x * 128;
    const int bn = blockIdx.y * 128;

    f32x4 acc[4][4];
#pragma unroll
    for (int i = 0; i < 4; ++i)
#pragma unroll
        for (int j = 0; j < 4; ++j) acc[i][j] = (f32x4){0.f, 0.f, 0.f, 0.f};

    const int kq = 4 * (t & 7);
    const int i2 = t >> 3;

    for (int kk = 0; kk < 1024; kk += 32) {
#pragma unroll
        for (int it = 0; it < 4; ++it) {
            int m = i2 + 32 * it;
            f32x4 x = *reinterpret_cast<const f32x4*>(&A[(size_t)(bm + m) * 1024 + kk + kq]);
            *reinterpret_cast<f16x4*>(sA + m * 64 + ((2 * kq) ^ (((m >> 1) & 3) << 4))) = cvt4h(x);
        }
        {
            int n0 = 4 * i2;
            f32x4 x[4];
#pragma unroll
            for (int r = 0; r < 4; ++r)
                x[r] = *reinterpret_cast<const f32x4*>(&B[(size_t)(kk + kq + r) * 1024 + bn + n0]);
#pragma unroll
            for (int j = 0; j < 4; ++j) {
                int n = n0 + j;
                union { f16x4 v; f16x2 h[2]; } s;
                s.h[0] = __builtin_amdgcn_cvt_pkrtz(x[0][j], x[1][j]);
                s.h[1] = __builtin_amdgcn_cvt_pkrtz(x[2][j], x[3][j]);
                *reinterpret_cast<f16x4*>(sB + n * 64 + ((2 * kq) ^ (((n >> 1) & 3) << 4))) = s.v;
            }
        }
        __syncthreads();
        f16x8 af[4], bfv[4];
        const int r0 = (w >> 1) * 64, c0 = (w & 1) * 64;
#pragma unroll
        for (int mt = 0; mt < 4; ++mt) {
            int m = r0 + 16 * mt + l15;
            af[mt] = *reinterpret_cast<f16x8*>(sA + m * 64 + ((16 * lg) ^ (((m >> 1) & 3) << 4)));
        }
#pragma unroll
        for (int nt = 0; nt < 4; ++nt) {
            int n = c0 + 16 * nt + l15;
            bfv[nt] = *reinterpret_cast<f16x8*>(sB + n * 64 + ((16 * lg) ^ (((n >> 1) & 3) << 4)));
        }
#pragma unroll
        for (int mt = 0; mt < 4; ++mt)
#pragma unroll
            for (int nt = 0; nt < 4; ++nt)
                acc[mt][nt] = MFMA16H(af[mt], bfv[nt], acc[mt][nt]);
        __syncthreads();
    }
#pragma unroll
    for (int mt = 0; mt < 4; ++mt)
#pragma unroll
        for (int nt = 0; nt < 4; ++nt)
#pragma unroll
            for (int rg = 0; rg < 4; ++rg) {
                int row = bm + (w >> 1) * 64 + 16 * mt + 4 * lg + rg;
                int col = bn + (w & 1) * 64 + 16 * nt + l15;
                C[(size_t)row * 1024 + col] = acc[mt][nt][rg];
            }
}

__global__ __launch_bounds__(256) void s_gemm_kernel(
    const float* __restrict__ Q, const float* __restrict__ enc, __fp16* __restrict__ S)
{
    __shared__ __align__(16) char sA[128 * 64];
    __shared__ __align__(16) char sB[128 * 64];
    const int t = threadIdx.x;
    const int w = t >> 6, l = t & 63;
    const int l15 = l & 15, lg = l >> 4;

    int rem = 135 - (int)blockIdx.x;
    int qt = 0;
    while (rem > qt) { rem -= qt + 1; ++qt; }
    const int kt = rem;
    const int b = blockIdx.y;
    const float* Arow = Q + ((size_t)b * 2048 + qt * 128) * 1024;
    const float* Brow = enc + ((size_t)b * 2048 + kt * 128) * 1024;

    f32x4 acc[4][4];
#pragma unroll
    for (int i = 0; i < 4; ++i)
#pragma unroll
        for (int j = 0; j < 4; ++j) acc[i][j] = (f32x4){0.f, 0.f, 0.f, 0.f};

    const int kq = 4 * (t & 7);
    const int i2 = t >> 3;

    for (int kk = 0; kk < 1024; kk += 32) {
#pragma unroll
        for (int it = 0; it < 4; ++it) {
            int m = i2 + 32 * it;
            int sw = (2 * kq) ^ (((m >> 1) & 3) << 4);
            f32x4 xa = *reinterpret_cast<const f32x4*>(&Arow[(size_t)m * 1024 + kk + kq]);
            f32x4 xb = *reinterpret_cast<const f32x4*>(&Brow[(size_t)m * 1024 + kk + kq]);
            *reinterpret_cast<f16x4*>(sA + m * 64 + sw) = cvt4h(xa);
            *reinterpret_cast<f16x4*>(sB + m * 64 + sw) = cvt4h(xb);
        }
        __syncthreads();
        f16x8 af[4], bfv[4];
        const int r0 = (w >> 1) * 64, c0 = (w & 1) * 64;
#pragma unroll
        for (int mt = 0; mt < 4; ++mt) {
            int m = r0 + 16 * mt + l15;
            af[mt] = *reinterpret_cast<f16x8*>(sA + m * 64 + ((16 * lg) ^ (((m >> 1) & 3) << 4)));
        }
#pragma unroll
        for (int nt = 0; nt < 4; ++nt) {
            int n = c0 + 16 * nt + l15;
            bfv[nt] = *reinterpret_cast<f16x8*>(sB + n * 64 + ((16 * lg) ^ (((n >> 1) & 3) << 4)));
        }
#pragma unroll
        for (int mt = 0; mt < 4; ++mt)
#pragma unroll
            for (int nt = 0; nt < 4; ++nt)
                acc[mt][nt] = MFMA16H(af[mt], bfv[nt], acc[mt][nt]);
        __syncthreads();
    }
    const int r0 = (w >> 1) * 64, c0 = (w & 1) * 64;
#pragma unroll
    for (int mt = 0; mt < 4; ++mt)
#pragma unroll
        for (int nt = 0; nt < 4; ++nt)
#pragma unroll
            for (int rg = 0; rg < 4; ++rg) {
                int rt = r0 + 16 * mt + 4 * lg + rg;
                int ct = c0 + 16 * nt + l15;
                float v = acc[mt][nt][rg];
                if (kt == qt && ct > rt) v = -30000.f;
                S[((size_t)b * 2048 + qt * 128 + rt) * 2048 + kt * 128 + ct] = (__fp16)v;
            }
}

__global__ __launch_bounds__(512) void pv_gemm_kernel(
    const __fp16* __restrict__ P, const float* __restrict__ enc, float* __restrict__ out)
{
    __shared__ __align__(16) char sA[128 * 128];
    __shared__ __align__(16) char sB[128 * 128];
    const int t = threadIdx.x;
    const int w = t >> 6, l = t & 63;
    const int l15 = l & 15, lg = (l >> 4) & 3;
    const int wq = w >> 2, wdv = w & 3;
    const int qtb = 15 - (int)blockIdx.x;
    const int dblk = blockIdx.y;
    const int b = blockIdx.z;
    const int q0 = 128 * qtb;
    const int nkv = 128 * (qtb + 1);
    const __fp16* Pbase = P + ((size_t)b * 2048 + q0) * 2048;
    const float* Eb = enc + (size_t)b * 2048 * 1024;

    f32x4 acc[4][2];
#pragma unroll
    for (int i = 0; i < 4; ++i)
#pragma unroll
        for (int j = 0; j < 2; ++j) acc[i][j] = (f32x4){0.f, 0.f, 0.f, 0.f};

    const int ar = t >> 2, aseg = t & 3;
    const int ba = t >> 5, bdq = t & 31;

    for (int kv0 = 0; kv0 < nkv; kv0 += 64) {
        __syncthreads();
        {
            const __fp16* src = Pbase + (size_t)ar * 2048 + kv0 + 16 * aseg;
            u32x4 v0 = *reinterpret_cast<const u32x4*>(src);
            u32x4 v1 = *reinterpret_cast<const u32x4*>(src + 8);
            const int sw = (ar & 7) << 4;
            *reinterpret_cast<u32x4*>(sA + ar * 128 + ((32 * aseg) ^ sw)) = v0;
            *reinterpret_cast<u32x4*>(sA + ar * 128 + ((32 * aseg + 16) ^ sw)) = v1;
        }
        {
            const float* src = Eb + (size_t)(kv0 + 4 * ba) * 1024 + 128 * dblk + 4 * bdq;
            f32x4 x0 = *reinterpret_cast<const f32x4*>(src);
            f32x4 x1 = *reinterpret_cast<const f32x4*>(src + 1024);
            f32x4 x2 = *reinterpret_cast<const f32x4*>(src + 2048);
            f32x4 x3 = *reinterpret_cast<const f32x4*>(src + 3072);
#pragma unroll
            for (int j = 0; j < 4; ++j) {
                int d = 4 * bdq + j;
                union { f16x4 v; f16x2 h[2]; } s;
                s.h[0] = __builtin_amdgcn_cvt_pkrtz(x0[j], x1[j]);
                s.h[1] = __builtin_amdgcn_cvt_pkrtz(x2[j], x3[j]);
                *reinterpret_cast<f16x4*>(sB + d * 128 + ((8 * ba) ^ ((d & 7) << 4))) = s.v;
            }
        }
        __syncthreads();
#pragma unroll
        for (int ks = 0; ks < 2; ++ks) {
            f16x8 afr[4], bfr[2];
#pragma unroll
            for (int mt = 0; mt < 4; ++mt) {
                int rr = 64 * wq + 16 * mt + l15;
                afr[mt] = *reinterpret_cast<f16x8*>(sA + rr * 128 + ((64 * ks + 16 * lg) ^ ((rr & 7) << 4)));
            }
#pragma unroll
            for (int nt = 0; nt < 2; ++nt) {
                int d = 32 * wdv + 16 * nt + l15;
                bfr[nt] = *reinterpret_cast<f16x8*>(sB + d * 128 + ((64 * ks + 16 * lg) ^ ((d & 7) << 4)));
            }
#pragma unroll
            for (int mt = 0; mt < 4; ++mt)
#pragma unroll
                for (int nt = 0; nt < 2; ++nt)
                    acc[mt][nt] = MFMA16H(afr[mt], bfr[nt], acc[mt][nt]);
        }
    }
#pragma unroll
    for (int mt = 0; mt < 4; ++mt)
#pragma unroll
        for (int nt = 0; nt < 2; ++nt)
#pragma unroll
            for (int rg = 0; rg < 4; ++rg) {
                size_t row = (size_t)b * 2048 + q0 + 64 * wq + 16 * mt + 4 * lg + rg;
                int col = 128 * dblk + 32 * wdv + 16 * nt + l15;
                out[row * 1024 + col] = acc[mt][nt][rg];
            }
}

// ---------------------------------------------------------------------------
extern "C" void kernel_launch(void* const* d_in, const int* in_sizes, int n_in,
                              void* d_out, int out_size, void* d_ws, size_t ws_size,
                              hipStream_t stream)
{
    const float* enc = (const float*)d_in[0];
    const float* R = (const float*)d_in[1];
    float* out = (float*)d_out;
    const size_t MB = 1u << 20;

    if (ws_size >= 98 * MB) {
        __fp16* S = (__fp16*)d_ws;                                  // 64MB
        __fp16* encT = (__fp16*)((char*)d_ws + 64 * MB);            // 32MB
        __fp16* Rt = (__fp16*)((char*)d_ws + 96 * MB);              // 2MB
        __fp16* Qh = (__fp16*)d_out;                                // 32MB
        __fp16* encH = (__fp16*)d_out + (size_t)16384 * 1024;       // 32MB

        transpose_cvt_kernel<<<dim3(32, 16, 8), 256, 0, stream>>>(enc, encT, encH, 2048, 1024);
        transpose_cvt_kernel<<<dim3(16, 16, 1), 256, 0, stream>>>(R, Rt, (__fp16*)nullptr, 1024, 1024);
        gemm_qr<<<dim3(1024), 256, 0, stream>>>(encH, Rt, Qh);
        gemm_s<<<dim3(1088), 256, 0, stream>>>(Qh, encH, S);
        softmax_kernel<<<dim3(512, 8), 256, 0, stream>>>(S);
        gemm_pv<<<dim3(1024), 256, 0, stream>>>(S, encT, out);
    } else {
        __fp16* S = (__fp16*)d_ws;
        qr_gemm_kernel<<<dim3(128, 8), 256, 0, stream>>>(enc, R, out);
        s_gemm_kernel<<<dim3(136, 8), 256, 0, stream>>>(out, enc, S);
        softmax_kernel<<<dim3(512, 8), 256, 0, stream>>>(S);
        pv_gemm_kernel<<<dim3(16, 8, 8), 512, 0, stream>>>(S, enc, out);
    }
}

// Round 7
// 191.202 us; speedup vs baseline: 5.6744x; 1.1450x over previous
//
#include <hip/hip_runtime.h>
#include <hip/hip_bf16.h>

// RelationAttn: out = softmax_causal((enc @ R) @ enc^T) @ enc
// enc: [8,2048,1024] f32, R: [1024,1024] f32, out: [8,2048,1024] f32
//
// f16 pipeline, all GEMMs m97-style (global_load_lds width-16, BK=64, 128^2),
// R7: + T2 XOR-swizzle (pre-swizzled global source, linear LDS dest, swizzled
//     ds_read) to kill the 16-way bank conflict of 128B LDS rows.
//   P0: enc -> enc_h (f16, d_out upper 32MB) + enc_t (f16 transposed, ws)
//   P1: R   -> R_t (f16 transposed, ws)
//   K1: Q_h = enc_h @ R_t^T      -> d_out lower 32MB (f16)
//   K2: S = Q_h @ enc_h^T causal -> ws (f16, lower-tri 128^2 tiles)
//   K3: P = softmax_row(S) in place
//   K4: out = P @ enc_t^T        -> d_out (f32, overwrites Q_h/enc_h)
// Fallback (ws < 98MB): R5 pipeline (f32-staged GEMMs).

typedef __attribute__((ext_vector_type(4))) float f32x4;
typedef __attribute__((ext_vector_type(4))) unsigned u32x4;
typedef __attribute__((ext_vector_type(8))) __fp16 f16x8;
typedef __attribute__((ext_vector_type(4))) __fp16 f16x4;
typedef __attribute__((ext_vector_type(2))) __fp16 f16x2;

#define MFMA16H(A, B, C) __builtin_amdgcn_mfma_f32_16x16x32_f16(A, B, C, 0, 0, 0)

__device__ __forceinline__ f16x4 cvt4h(f32x4 a) {
    union { f16x4 v; f16x2 h[2]; } r;
    r.h[0] = __builtin_amdgcn_cvt_pkrtz(a[0], a[1]);
    r.h[1] = __builtin_amdgcn_cvt_pkrtz(a[2], a[3]);
    return r.v;
}

// async global->LDS, 16B per lane; lds dest = wave-uniform base + lane*16
__device__ __forceinline__ void gload16(const void* g, void* l) {
    __builtin_amdgcn_global_load_lds(
        (const __attribute__((address_space(1))) unsigned*)g,
        (__attribute__((address_space(3))) unsigned*)l, 16, 0, 0);
}

// ---------------------------------------------------------------------------
// P0/P1: transpose + convert. src f32 [bz][R][C] -> dstT f16 [bz][C][R]
// and (if dstH) dstH f16 [bz][R][C]. 64x64 tiles, swizzled LDS.
// ---------------------------------------------------------------------------
__global__ __launch_bounds__(256) void transpose_cvt_kernel(
    const float* __restrict__ src, __fp16* __restrict__ dstT,
    __fp16* __restrict__ dstH, int R, int C)
{
    __shared__ __align__(16) char lt[64 * 128];  // [r][c] f16, XOR-swizzled
    const int t = threadIdx.x;
    const int bz = blockIdx.z;
    const int r0 = blockIdx.x * 64, c0 = blockIdx.y * 64;
    const size_t so = (size_t)bz * R * C;
    const int tr = t >> 4;
    const int tc4 = (t & 15) * 4;
#pragma unroll
    for (int p = 0; p < 4; ++p) {
        int rl = tr + 16 * p;
        f32x4 x = *(const f32x4*)(src + so + (size_t)(r0 + rl) * C + c0 + tc4);
        f16x4 h = cvt4h(x);
        if (dstH) *(f16x4*)(dstH + so + (size_t)(r0 + rl) * C + c0 + tc4) = h;
        *(f16x4*)(lt + rl * 128 + ((tc4 * 2) ^ ((rl & 7) << 4))) = h;
    }
    __syncthreads();
#pragma unroll
    for (int p = 0; p < 4; ++p) {
        int dl = tr + 16 * p;
#pragma unroll
        for (int j = 0; j < 4; ++j) {
            int kl = (t & 15) + 16 * j;
            __fp16 v = *(const __fp16*)(lt + kl * 128 + ((dl * 2) ^ ((kl & 7) << 4)));
            dstT[so + (size_t)(c0 + dl) * R + r0 + kl] = v;
        }
    }
}

// ---------------------------------------------------------------------------
// Unified f16 GEMM core: C(128x128) = A(128xK) @ B(128xK)^T, m97 structure
// + st-style XOR swizzle. LDS rows are 128B; logical byte b of row r lives at
// physical byte (b ^ ((r&7)<<4)). global_load_lds writes linearly, so the
// SOURCE granule per lane is pre-permuted: lane l stages granule (l&7)^(l>>3)
// of row 32w+8i+(l>>3) into physical slot l&7. Reads apply the same XOR.
// CMODE: 0 = f16 out; 1 = f16 out + causal diag mask; 2 = f32 out.
// ---------------------------------------------------------------------------
template <int CMODE>
__device__ __forceinline__ void gemm_core(
    const __fp16* __restrict__ A, const __fp16* __restrict__ B,
    char* __restrict__ Cptr, int ldA, int ldB, int ldC, int K, bool diag)
{
    __shared__ __align__(16) char sA[128 * 128];  // 128 rows x 64 f16 (16KB)
    __shared__ __align__(16) char sB[128 * 128];
    const int t = threadIdx.x;
    const int w = t >> 6, l = t & 63;
    const int l15 = l & 15, lg = l >> 4;
    const int r0 = (w >> 1) * 64, c0 = (w & 1) * 64;
    const int swz = (l15 & 7) << 4;   // read-side XOR (row&7 == l15&7)

    f32x4 acc[4][4];
#pragma unroll
    for (int i = 0; i < 4; ++i)
#pragma unroll
        for (int j = 0; j < 4; ++j) acc[i][j] = (f32x4){0.f, 0.f, 0.f, 0.f};

    // staging: wave w rows 32w..32w+31; instr i rows 32w+8i..+7;
    // lane l: row += l>>3, SOURCE granule (l&7)^(l>>3) (inverse swizzle).
    const int strow = 32 * w + (l >> 3);
    const int gsrc = (((l & 7) ^ (l >> 3)) << 3);  // element offset (x8 f16)
    const __fp16* pa = A + (size_t)strow * ldA + gsrc;
    const __fp16* pb = B + (size_t)strow * ldB + gsrc;

    for (int kk = 0; kk < K; kk += 64) {
        __syncthreads();  // prev compute done reading LDS
#pragma unroll
        for (int i = 0; i < 4; ++i) {
            gload16(pa + (size_t)(8 * i) * ldA + kk, sA + w * 4096 + i * 1024);
            gload16(pb + (size_t)(8 * i) * ldB + kk, sB + w * 4096 + i * 1024);
        }
        __syncthreads();  // drains vmcnt before barrier -> staging visible
#pragma unroll
        for (int ks = 0; ks < 2; ++ks) {
            f16x8 af[4], bf[4];
#pragma unroll
            for (int mt = 0; mt < 4; ++mt)
                af[mt] = *(const f16x8*)(sA + (r0 + 16 * mt + l15) * 128 + ((64 * ks + 16 * lg) ^ swz));
#pragma unroll
            for (int nt = 0; nt < 4; ++nt)
                bf[nt] = *(const f16x8*)(sB + (c0 + 16 * nt + l15) * 128 + ((64 * ks + 16 * lg) ^ swz));
#pragma unroll
            for (int mt = 0; mt < 4; ++mt)
#pragma unroll
                for (int nt = 0; nt < 4; ++nt)
                    acc[mt][nt] = MFMA16H(af[mt], bf[nt], acc[mt][nt]);
        }
    }
    // C/D layout: col = l15, row = 4*lg + rg
#pragma unroll
    for (int mt = 0; mt < 4; ++mt)
#pragma unroll
        for (int nt = 0; nt < 4; ++nt)
#pragma unroll
            for (int rg = 0; rg < 4; ++rg) {
                int rr = r0 + 16 * mt + 4 * lg + rg;
                int cc = c0 + 16 * nt + l15;
                float v = acc[mt][nt][rg];
                if (CMODE == 2) {
                    *(float*)(Cptr + ((size_t)rr * ldC + cc) * 4) = v;
                } else {
                    if (CMODE == 1 && diag && cc > rr) v = -30000.f;
                    *(__fp16*)(Cptr + ((size_t)rr * ldC + cc) * 2) = (__fp16)v;
                }
            }
}

// K1: Q_h = enc_h @ R_t^T  (16384x1024 @ 1024x1024)
__global__ __launch_bounds__(256) void gemm_qr(
    const __fp16* __restrict__ encH, const __fp16* __restrict__ Rt,
    __fp16* __restrict__ Qh)
{
    const int bm = ((int)blockIdx.x >> 3) * 128;
    const int bn = ((int)blockIdx.x & 7) * 128;
    gemm_core<0>(encH + (size_t)bm * 1024, Rt + (size_t)bn * 1024,
                 (char*)(Qh + (size_t)bm * 1024 + bn), 1024, 1024, 1024, 1024, false);
}

// K2: S = Q_h @ enc_h^T, causal lower-tri tiles. batch = bid&7 (XCD affinity).
__global__ __launch_bounds__(256) void gemm_s(
    const __fp16* __restrict__ Qh, const __fp16* __restrict__ encH,
    __fp16* __restrict__ S)
{
    const int b = (int)blockIdx.x & 7;
    int rem = 135 - ((int)blockIdx.x >> 3);
    int qt = 0;
    while (rem > qt) { rem -= qt + 1; ++qt; }
    const int kt = rem;
    const size_t bo = (size_t)b * 2048 * 1024;
    const size_t so = (size_t)b * 2048 * 2048;
    gemm_core<1>(Qh + bo + (size_t)(qt * 128) * 1024,
                 encH + bo + (size_t)(kt * 128) * 1024,
                 (char*)(S + so + (size_t)(qt * 128) * 2048 + kt * 128),
                 1024, 1024, 2048, 1024, qt == kt);
}

// K4: out = P @ enc_t^T. Variable K = 128*(qtb+1), heavy-first.
__global__ __launch_bounds__(256) void gemm_pv(
    const __fp16* __restrict__ P, const __fp16* __restrict__ encT,
    float* __restrict__ out)
{
    const int b = (int)blockIdx.x & 7;
    const int r = (int)blockIdx.x >> 3;      // 0..127
    const int qtb = 15 - (r >> 3);
    const int dblk = r & 7;
    const size_t so = (size_t)b * 2048 * 2048;
    const size_t to = (size_t)b * 1024 * 2048;
    const int K = 128 * (qtb + 1);
    gemm_core<2>(P + so + (size_t)(qtb * 128) * 2048,
                 encT + to + (size_t)(dblk * 128) * 2048,
                 (char*)(out + (size_t)b * 2048 * 1024 + (size_t)(qtb * 128) * 1024 + dblk * 128),
                 2048, 2048, 1024, K, false);
}

// ---------------------------------------------------------------------------
// K3: in-place row softmax over S (f16). One wave per row; L = roundup(r+1,128).
// ---------------------------------------------------------------------------
__global__ __launch_bounds__(256) void softmax_kernel(__fp16* __restrict__ S)
{
    const int t = threadIdx.x;
    const int wv = t >> 6, l = t & 63;
    const int r = blockIdx.x * 4 + wv;
    const int b = blockIdx.y;
    __fp16* row = S + ((size_t)b * 2048 + r) * 2048;
    const int L = ((r >> 7) + 1) << 7;

    float v[4][8];
    float mx = -1e30f;
#pragma unroll
    for (int i = 0; i < 4; ++i) {
        int c0 = 8 * l + 512 * i;
        if (c0 < L) {
            f16x8 h = *reinterpret_cast<const f16x8*>(row + c0);
#pragma unroll
            for (int j = 0; j < 8; ++j) { v[i][j] = (float)h[j]; mx = fmaxf(mx, v[i][j]); }
        } else {
#pragma unroll
            for (int j = 0; j < 8; ++j) v[i][j] = -1e30f;
        }
    }
#pragma unroll
    for (int off = 1; off < 64; off <<= 1) mx = fmaxf(mx, __shfl_xor(mx, off));
    float sm = 0.f;
#pragma unroll
    for (int i = 0; i < 4; ++i)
#pragma unroll
        for (int j = 0; j < 8; ++j) { v[i][j] = __expf(v[i][j] - mx); sm += v[i][j]; }
#pragma unroll
    for (int off = 1; off < 64; off <<= 1) sm += __shfl_xor(sm, off);
    const float inv = 1.f / sm;
#pragma unroll
    for (int i = 0; i < 4; ++i) {
        int c0 = 8 * l + 512 * i;
        if (c0 < L) {
            union { f16x8 v8; f16x2 h[4]; } o;
#pragma unroll
            for (int j = 0; j < 4; ++j)
                o.h[j] = __builtin_amdgcn_cvt_pkrtz(v[i][2 * j] * inv, v[i][2 * j + 1] * inv);
            *reinterpret_cast<f16x8*>(row + c0) = o.v8;
        }
    }
}

// ===========================================================================
// Fallback path (R5): f32-staged GEMMs, used only if ws < 98MB.
// ===========================================================================
__global__ __launch_bounds__(256) void qr_gemm_kernel(
    const float* __restrict__ A, const float* __restrict__ B, float* C)
{
    __shared__ __align__(16) char sA[128 * 64];
    __shared__ __align__(16) char sB[128 * 64];
    const int t = threadIdx.x;
    const int w = t >> 6, l = t & 63;
    const int l15 = l & 15, lg = l >> 4;
    const int bm = blockIdx.x * 128;
    const int bn = blockIdx.y * 128;

    f32x4 acc[4][4];
#pragma unroll
    for (int i = 0; i < 4; ++i)
#pragma unroll
        for (int j = 0; j < 4; ++j) acc[i][j] = (f32x4){0.f, 0.f, 0.f, 0.f};

    const int kq = 4 * (t & 7);
    const int i2 = t >> 3;

    for (int kk = 0; kk < 1024; kk += 32) {
#pragma unroll
        for (int it = 0; it < 4; ++it) {
            int m = i2 + 32 * it;
            f32x4 x = *reinterpret_cast<const f32x4*>(&A[(size_t)(bm + m) * 1024 + kk + kq]);
            *reinterpret_cast<f16x4*>(sA + m * 64 + ((2 * kq) ^ (((m >> 1) & 3) << 4))) = cvt4h(x);
        }
        {
            int n0 = 4 * i2;
            f32x4 x[4];
#pragma unroll
            for (int r = 0; r < 4; ++r)
                x[r] = *reinterpret_cast<const f32x4*>(&B[(size_t)(kk + kq + r) * 1024 + bn + n0]);
#pragma unroll
            for (int j = 0; j < 4; ++j) {
                int n = n0 + j;
                union { f16x4 v; f16x2 h[2]; } s;
                s.h[0] = __builtin_amdgcn_cvt_pkrtz(x[0][j], x[1][j]);
                s.h[1] = __builtin_amdgcn_cvt_pkrtz(x[2][j], x[3][j]);
                *reinterpret_cast<f16x4*>(sB + n * 64 + ((2 * kq) ^ (((n >> 1) & 3) << 4))) = s.v;
            }
        }
        __syncthreads();
        f16x8 af[4], bfv[4];
        const int r0 = (w >> 1) * 64, c0 = (w & 1) * 64;
#pragma unroll
        for (int mt = 0; mt < 4; ++mt) {
            int m = r0 + 16 * mt + l15;
            af[mt] = *reinterpret_cast<f16x8*>(sA + m * 64 + ((16 * lg) ^ (((m >> 1) & 3) << 4)));
        }
#pragma unroll
        for (int nt = 0; nt < 4; ++nt) {
            int n = c0 + 16 * nt + l15;
            bfv[nt] = *reinterpret_cast<f16x8*>(sB + n * 64 + ((16 * lg) ^ (((n >> 1) & 3) << 4)));
        }
#pragma unroll
        for (int mt = 0; mt < 4; ++mt)
#pragma unroll
            for (int nt = 0; nt < 4; ++nt)
                acc[mt][nt] = MFMA16H(af[mt], bfv[nt], acc[mt][nt]);
        __syncthreads();
    }
#pragma unroll
    for (int mt = 0; mt < 4; ++mt)
#pragma unroll
        for (int nt = 0; nt < 4; ++nt)
#pragma unroll
            for (int rg = 0; rg < 4; ++rg) {
                int row = bm + (w >> 1) * 64 + 16 * mt + 4 * lg + rg;
                int col = bn + (w & 1) * 64 + 16 * nt + l15;
                C[(size_t)row * 1024 + col] = acc[mt][nt][rg];
            }
}

__global__ __launch_bounds__(256) void s_gemm_kernel(
    const float* __restrict__ Q, const float* __restrict__ enc, __fp16* __restrict__ S)
{
    __shared__ __align__(16) char sA[128 * 64];
    __shared__ __align__(16) char sB[128 * 64];
    const int t = threadIdx.x;
    const int w = t >> 6, l = t & 63;
    const int l15 = l & 15, lg = l >> 4;

    int rem = 135 - (int)blockIdx.x;
    int qt = 0;
    while (rem > qt) { rem -= qt + 1; ++qt; }
    const int kt = rem;
    const int b = blockIdx.y;
    const float* Arow = Q + ((size_t)b * 2048 + qt * 128) * 1024;
    const float* Brow = enc + ((size_t)b * 2048 + kt * 128) * 1024;

    f32x4 acc[4][4];
#pragma unroll
    for (int i = 0; i < 4; ++i)
#pragma unroll
        for (int j = 0; j < 4; ++j) acc[i][j] = (f32x4){0.f, 0.f, 0.f, 0.f};

    const int kq = 4 * (t & 7);
    const int i2 = t >> 3;

    for (int kk = 0; kk < 1024; kk += 32) {
#pragma unroll
        for (int it = 0; it < 4; ++it) {
            int m = i2 + 32 * it;
            int sw = (2 * kq) ^ (((m >> 1) & 3) << 4);
            f32x4 xa = *reinterpret_cast<const f32x4*>(&Arow[(size_t)m * 1024 + kk + kq]);
            f32x4 xb = *reinterpret_cast<const f32x4*>(&Brow[(size_t)m * 1024 + kk + kq]);
            *reinterpret_cast<f16x4*>(sA + m * 64 + sw) = cvt4h(xa);
            *reinterpret_cast<f16x4*>(sB + m * 64 + sw) = cvt4h(xb);
        }
        __syncthreads();
        f16x8 af[4], bfv[4];
        const int r0 = (w >> 1) * 64, c0 = (w & 1) * 64;
#pragma unroll
        for (int mt = 0; mt < 4; ++mt) {
            int m = r0 + 16 * mt + l15;
            af[mt] = *reinterpret_cast<f16x8*>(sA + m * 64 + ((16 * lg) ^ (((m >> 1) & 3) << 4)));
        }
#pragma unroll
        for (int nt = 0; nt < 4; ++nt) {
            int n = c0 + 16 * nt + l15;
            bfv[nt] = *reinterpret_cast<f16x8*>(sB + n * 64 + ((16 * lg) ^ (((n >> 1) & 3) << 4)));
        }
#pragma unroll
        for (int mt = 0; mt < 4; ++mt)
#pragma unroll
            for (int nt = 0; nt < 4; ++nt)
                acc[mt][nt] = MFMA16H(af[mt], bfv[nt], acc[mt][nt]);
        __syncthreads();
    }
    const int r0 = (w >> 1) * 64, c0 = (w & 1) * 64;
#pragma unroll
    for (int mt = 0; mt < 4; ++mt)
#pragma unroll
        for (int nt = 0; nt < 4; ++nt)
#pragma unroll
            for (int rg = 0; rg < 4; ++rg) {
                int rt = r0 + 16 * mt + 4 * lg + rg;
                int ct = c0 + 16 * nt + l15;
                float v = acc[mt][nt][rg];
                if (kt == qt && ct > rt) v = -30000.f;
                S[((size_t)b * 2048 + qt * 128 + rt) * 2048 + kt * 128 + ct] = (__fp16)v;
            }
}

__global__ __launch_bounds__(512) void pv_gemm_kernel(
    const __fp16* __restrict__ P, const float* __restrict__ enc, float* __restrict__ out)
{
    __shared__ __align__(16) char sA[128 * 128];
    __shared__ __align__(16) char sB[128 * 128];
    const int t = threadIdx.x;
    const int w = t >> 6, l = t & 63;
    const int l15 = l & 15, lg = (l >> 4) & 3;
    const int wq = w >> 2, wdv = w & 3;
    const int qtb = 15 - (int)blockIdx.x;
    const int dblk = blockIdx.y;
    const int b = blockIdx.z;
    const int q0 = 128 * qtb;
    const int nkv = 128 * (qtb + 1);
    const __fp16* Pbase = P + ((size_t)b * 2048 + q0) * 2048;
    const float* Eb = enc + (size_t)b * 2048 * 1024;

    f32x4 acc[4][2];
#pragma unroll
    for (int i = 0; i < 4; ++i)
#pragma unroll
        for (int j = 0; j < 2; ++j) acc[i][j] = (f32x4){0.f, 0.f, 0.f, 0.f};

    const int ar = t >> 2, aseg = t & 3;
    const int ba = t >> 5, bdq = t & 31;

    for (int kv0 = 0; kv0 < nkv; kv0 += 64) {
        __syncthreads();
        {
            const __fp16* src = Pbase + (size_t)ar * 2048 + kv0 + 16 * aseg;
            u32x4 v0 = *reinterpret_cast<const u32x4*>(src);
            u32x4 v1 = *reinterpret_cast<const u32x4*>(src + 8);
            const int sw = (ar & 7) << 4;
            *reinterpret_cast<u32x4*>(sA + ar * 128 + ((32 * aseg) ^ sw)) = v0;
            *reinterpret_cast<u32x4*>(sA + ar * 128 + ((32 * aseg + 16) ^ sw)) = v1;
        }
        {
            const float* src = Eb + (size_t)(kv0 + 4 * ba) * 1024 + 128 * dblk + 4 * bdq;
            f32x4 x0 = *reinterpret_cast<const f32x4*>(src);
            f32x4 x1 = *reinterpret_cast<const f32x4*>(src + 1024);
            f32x4 x2 = *reinterpret_cast<const f32x4*>(src + 2048);
            f32x4 x3 = *reinterpret_cast<const f32x4*>(src + 3072);
#pragma unroll
            for (int j = 0; j < 4; ++j) {
                int d = 4 * bdq + j;
                union { f16x4 v; f16x2 h[2]; } s;
                s.h[0] = __builtin_amdgcn_cvt_pkrtz(x0[j], x1[j]);
                s.h[1] = __builtin_amdgcn_cvt_pkrtz(x2[j], x3[j]);
                *reinterpret_cast<f16x4*>(sB + d * 128 + ((8 * ba) ^ ((d & 7) << 4))) = s.v;
            }
        }
        __syncthreads();
#pragma unroll
        for (int ks = 0; ks < 2; ++ks) {
            f16x8 afr[4], bfr[2];
#pragma unroll
            for (int mt = 0; mt < 4; ++mt) {
                int rr = 64 * wq + 16 * mt + l15;
                afr[mt] = *reinterpret_cast<f16x8*>(sA + rr * 128 + ((64 * ks + 16 * lg) ^ ((rr & 7) << 4)));
            }
#pragma unroll
            for (int nt = 0; nt < 2; ++nt) {
                int d = 32 * wdv + 16 * nt + l15;
                bfr[nt] = *reinterpret_cast<f16x8*>(sB + d * 128 + ((64 * ks + 16 * lg) ^ ((d & 7) << 4)));
            }
#pragma unroll
            for (int mt = 0; mt < 4; ++mt)
#pragma unroll
                for (int nt = 0; nt < 2; ++nt)
                    acc[mt][nt] = MFMA16H(afr[mt], bfr[nt], acc[mt][nt]);
        }
    }
#pragma unroll
    for (int mt = 0; mt < 4; ++mt)
#pragma unroll
        for (int nt = 0; nt < 2; ++nt)
#pragma unroll
            for (int rg = 0; rg < 4; ++rg) {
                size_t row = (size_t)b * 2048 + q0 + 64 * wq + 16 * mt + 4 * lg + rg;
                int col = 128 * dblk + 32 * wdv + 16 * nt + l15;
                out[row * 1024 + col] = acc[mt][nt][rg];
            }
}

// ---------------------------------------------------------------------------
extern "C" void kernel_launch(void* const* d_in, const int* in_sizes, int n_in,
                              void* d_out, int out_size, void* d_ws, size_t ws_size,
                              hipStream_t stream)
{
    const float* enc = (const float*)d_in[0];
    const float* R = (const float*)d_in[1];
    float* out = (float*)d_out;
    const size_t MB = 1u << 20;

    if (ws_size >= 98 * MB) {
        __fp16* S = (__fp16*)d_ws;                                  // 64MB
        __fp16* encT = (__fp16*)((char*)d_ws + 64 * MB);            // 32MB
        __fp16* Rt = (__fp16*)((char*)d_ws + 96 * MB);              // 2MB
        __fp16* Qh = (__fp16*)d_out;                                // 32MB
        __fp16* encH = (__fp16*)d_out + (size_t)16384 * 1024;       // 32MB

        transpose_cvt_kernel<<<dim3(32, 16, 8), 256, 0, stream>>>(enc, encT, encH, 2048, 1024);
        transpose_cvt_kernel<<<dim3(16, 16, 1), 256, 0, stream>>>(R, Rt, (__fp16*)nullptr, 1024, 1024);
        gemm_qr<<<dim3(1024), 256, 0, stream>>>(encH, Rt, Qh);
        gemm_s<<<dim3(1088), 256, 0, stream>>>(Qh, encH, S);
        softmax_kernel<<<dim3(512, 8), 256, 0, stream>>>(S);
        gemm_pv<<<dim3(1024), 256, 0, stream>>>(S, encT, out);
    } else {
        __fp16* S = (__fp16*)d_ws;
        qr_gemm_kernel<<<dim3(128, 8), 256, 0, stream>>>(enc, R, out);
        s_gemm_kernel<<<dim3(136, 8), 256, 0, stream>>>(out, enc, S);
        softmax_kernel<<<dim3(512, 8), 256, 0, stream>>>(S);
        pv_gemm_kernel<<<dim3(16, 8, 8), 512, 0, stream>>>(S, enc, out);
    }
}